// Round 4
// baseline (1076.016 us; speedup 1.0000x reference)
//
#include <hip/hip_runtime.h>
#include <hip/hip_bf16.h>
#include <math.h>

#define NB 8
#define NIN 3136
#define NOUT 784
#define DIN 96
#define DOUT 192
#define HID 384
#define TOK_IN (NB*NIN)    // 25088
#define TOK_OUT (NB*NOUT)  // 6272

// ---------------- generic LayerNorm over last dim (D<=192), one row per block (64 thr)
__global__ __launch_bounds__(64) void k_ln(const float* __restrict__ in, float* __restrict__ out,
                                           const float* __restrict__ g, const float* __restrict__ bb,
                                           int D) {
  int row = blockIdx.x;
  const float* ip = in + (size_t)row * D;
  float* op = out + (size_t)row * D;
  int t = threadIdx.x;
  float v0 = 0.f, v1 = 0.f, v2 = 0.f, s = 0.f, sq = 0.f;
  if (t < D)       { v0 = ip[t];       s += v0; sq += v0*v0; }
  if (t + 64 < D)  { v1 = ip[t+64];    s += v1; sq += v1*v1; }
  if (t + 128 < D) { v2 = ip[t+128];   s += v2; sq += v2*v2; }
  #pragma unroll
  for (int off = 32; off; off >>= 1) { s += __shfl_xor(s, off); sq += __shfl_xor(sq, off); }
  float mu = s / (float)D;
  float var = sq / (float)D - mu*mu;
  float rs = rsqrtf(var + 1e-5f);
  if (t < D)       op[t]     = (v0-mu)*rs*g[t]     + bb[t];
  if (t + 64 < D)  op[t+64]  = (v1-mu)*rs*g[t+64]  + bb[t+64];
  if (t + 128 < D) op[t+128] = (v2-mu)*rs*g[t+128] + bb[t+128];
}

// ---------------- weight transposes (once per launch)
// wct  : [kh][kw][ci4][co][4]
// wkv4 : [e4][288][4]   (cols 0..95 = k_w, 96..287 = v_w)
// qw4  : [e4][96][4]
// w1_4 : [e4][384][4]
// w2_4 : [h4][192][4]
__global__ void k_tr(const float* __restrict__ cw, const float* __restrict__ kw,
                     const float* __restrict__ vw, const float* __restrict__ qw,
                     const float* __restrict__ w1, const float* __restrict__ w2,
                     float* __restrict__ wct, float* __restrict__ wkv4, float* __restrict__ qw4,
                     float* __restrict__ w1_4, float* __restrict__ w2_4) {
  int i = blockIdx.x * 256 + threadIdx.x;
  if (i < 165888) {                               // wct[kh][kw][ci4][co][q]
    int q = i & 3; int t1 = i >> 2;
    int co = t1 % 192; int t2 = t1 / 192;
    int ci4 = t2 % 24; int t3 = t2 / 24;
    int kwi = t3 % 3; int kh = t3 / 3;
    wct[i] = cw[((co*96 + ci4*4 + q)*3 + kh)*3 + kwi];
  } else if (i < 165888 + 27648) {
    int j = i - 165888; int q = j & 3; int rest = j >> 2;
    int o = rest % 288; int e = (rest / 288)*4 + q;
    wkv4[j] = (o < 96) ? kw[o*96 + e] : vw[(o-96)*96 + e];
  } else if (i < 165888 + 27648 + 18432) {
    int j = i - 165888 - 27648; int q = j & 3; int rest = j >> 2;
    int o = rest % 96; int e = (rest / 96)*4 + q;
    qw4[j] = qw[o*192 + e];
  } else if (i < 165888 + 27648 + 18432 + 73728) {
    int j = i - 165888 - 27648 - 18432; int q = j & 3; int rest = j >> 2;
    int hh = rest % 384; int e = (rest / 384)*4 + q;
    w1_4[j] = w1[hh*192 + e];
  } else if (i < 165888 + 27648 + 18432 + 73728 + 73728) {
    int j = i - 165888 - 27648 - 18432 - 73728; int q = j & 3; int rest = j >> 2;
    int o = rest % 192; int h = (rest / 192)*4 + q;
    w2_4[j] = w2[o*384 + h];
  }
}

// ---------------- strided 3x3 conv seed, LDS-staged implicit GEMM.
// grid (ho=28, wo_half=2, b*2+co_half=16); 224 thr = 7 groups x 32 lanes.
// group tg: wo = W0 + 2tg + {0,1}; lane ol: co = co_half*96 + ol + 32j, j<3.
__global__ __launch_bounds__(224) void k_conv(const float* __restrict__ x,
                                              const float* __restrict__ wct,
                                              float* __restrict__ seed) {
  __shared__ float xs[3][30][96];   // 34.5 KB
  int ho = blockIdx.x, wh = blockIdx.y;
  int b = blockIdx.z >> 1, half = blockIdx.z & 1;
  int W0 = wh * 14;
  int t = threadIdx.x;
  for (int idx = t; idx < 3*30*96; idx += 224) {
    int ci = idx % 96; int rest = idx / 96;
    int col = rest % 30; int kh = rest / 30;
    int h = 2*ho - 1 + kh;
    int c = 2*W0 - 1 + col;
    float v = 0.f;
    if (h >= 0 && h < 56 && c >= 0 && c < 56)
      v = x[((size_t)b*NIN + h*56 + c)*DIN + ci];
    xs[kh][col][ci] = v;
  }
  __syncthreads();
  int ol = t & 31, tg = t >> 5;       // tg in [0,7)
  int co = half*96 + ol;
  float acc[2][3];
  #pragma unroll
  for (int i = 0; i < 2; i++) { acc[i][0]=0.f; acc[i][1]=0.f; acc[i][2]=0.f; }
  #pragma unroll
  for (int kh = 0; kh < 3; kh++) {
    #pragma unroll
    for (int kwv = 0; kwv < 3; kwv++) {
      #pragma unroll 4
      for (int ci4 = 0; ci4 < 24; ci4++) {
        const float4* wp = (const float4*)wct + (((kh*3 + kwv)*24 + ci4)*192 + co);
        float4 w0 = wp[0], w1 = wp[32], w2 = wp[64];
        float4 x0 = *(const float4*)&xs[kh][4*tg + kwv][ci4*4];
        float4 x1 = *(const float4*)&xs[kh][4*tg + 2 + kwv][ci4*4];
        acc[0][0] += x0.x*w0.x + x0.y*w0.y + x0.z*w0.z + x0.w*w0.w;
        acc[0][1] += x0.x*w1.x + x0.y*w1.y + x0.z*w1.z + x0.w*w1.w;
        acc[0][2] += x0.x*w2.x + x0.y*w2.y + x0.z*w2.z + x0.w*w2.w;
        acc[1][0] += x1.x*w0.x + x1.y*w0.y + x1.z*w0.z + x1.w*w0.w;
        acc[1][1] += x1.x*w1.x + x1.y*w1.y + x1.z*w1.z + x1.w*w1.w;
        acc[1][2] += x1.x*w2.x + x1.y*w2.y + x1.z*w2.z + x1.w*w2.w;
      }
    }
  }
  #pragma unroll
  for (int i = 0; i < 2; i++)
    #pragma unroll
    for (int j = 0; j < 3; j++)
      seed[((size_t)b*NOUT + ho*28 + W0 + 2*tg + i)*DOUT + co + 32*j] = acc[i][j];
}

// ---------------- kv = xn @ [k_w|v_w]^T. 32 tokens/block, 512 thr (16 groups TM=2 TN=9)
__global__ __launch_bounds__(512) void k_kv(const float* __restrict__ xn,
                                            const float* __restrict__ wkv4,
                                            float* __restrict__ kvb) {
  __shared__ float xt[32][100];
  int tok0 = blockIdx.x * 32;
  int t = threadIdx.x;
  for (int i = t; i < 32*DIN; i += 512) {
    int tok = i / DIN, e = i % DIN;
    xt[tok][e] = xn[(size_t)(tok0 + tok)*DIN + e];
  }
  __syncthreads();
  int ol = t & 31, tg = t >> 5;     // 16 groups x 2 tokens
  float acc[2][9];
  #pragma unroll
  for (int i = 0; i < 2; i++)
    #pragma unroll
    for (int j = 0; j < 9; j++) acc[i][j] = 0.f;
  const float4* wq = (const float4*)wkv4;
  for (int e4 = 0; e4 < 24; e4++) {
    float4 w[9];
    #pragma unroll
    for (int j = 0; j < 9; j++) w[j] = wq[(size_t)e4*288 + ol + 32*j];
    #pragma unroll
    for (int i = 0; i < 2; i++) {
      float4 xv = *(const float4*)&xt[tg*2+i][e4*4];
      #pragma unroll
      for (int j = 0; j < 9; j++)
        acc[i][j] += xv.x*w[j].x + xv.y*w[j].y + xv.z*w[j].z + xv.w*w[j].w;
    }
  }
  #pragma unroll
  for (int i = 0; i < 2; i++)
    #pragma unroll
    for (int j = 0; j < 9; j++)
      kvb[(size_t)(tok0 + tg*2 + i)*288 + ol + 32*j] = acc[i][j];
}

// ---------------- q = LN(x_out) @ q_w^T, LN fused. 8 tokens/block (784 blocks), 256 thr
__global__ __launch_bounds__(256) void k_q(const float* __restrict__ xo,
                                           const float* __restrict__ qw4,
                                           const float* __restrict__ lng, const float* __restrict__ lnb,
                                           float* __restrict__ qb) {
  __shared__ float xt[8][196];
  int tok0 = blockIdx.x * 8;
  int t = threadIdx.x;
  int ol = t & 31, g = t >> 5;      // group g = token g
  // load own token row + LN stats (wave-private LDS: no block barrier needed)
  const float* ip = xo + (size_t)(tok0 + g)*DOUT;
  float v[6], s = 0.f, sq = 0.f;
  #pragma unroll
  for (int jj = 0; jj < 6; jj++) {
    float vv = ip[ol + 32*jj];
    v[jj] = vv; s += vv; sq += vv*vv;
  }
  #pragma unroll
  for (int off = 16; off; off >>= 1) { s += __shfl_xor(s, off, 32); sq += __shfl_xor(sq, off, 32); }
  float mu = s * (1.f/192.f);
  float var = sq * (1.f/192.f) - mu*mu;
  float rs = rsqrtf(var + 1e-5f);
  #pragma unroll
  for (int jj = 0; jj < 6; jj++) {
    int e = ol + 32*jj;
    xt[g][e] = (v[jj]-mu)*rs*lng[e] + lnb[e];
  }
  // GEMM (reads only own group's row -> wave-lockstep safe)
  float acc[3] = {0.f, 0.f, 0.f};
  const float4* wq = (const float4*)qw4;
  for (int e4 = 0; e4 < 48; e4++) {
    float4 w0 = wq[(size_t)e4*96 + ol];
    float4 w1 = wq[(size_t)e4*96 + ol + 32];
    float4 w2 = wq[(size_t)e4*96 + ol + 64];
    float4 xv = *(const float4*)&xt[g][e4*4];
    acc[0] += xv.x*w0.x + xv.y*w0.y + xv.z*w0.z + xv.w*w0.w;
    acc[1] += xv.x*w1.x + xv.y*w1.y + xv.z*w1.z + xv.w*w1.w;
    acc[2] += xv.x*w2.x + xv.y*w2.y + xv.z*w2.z + xv.w*w2.w;
  }
  #pragma unroll
  for (int j = 0; j < 3; j++)
    qb[(size_t)(tok0 + g)*DIN + ol + 32*j] = acc[j];
}

// ---------------- window helper
__device__ __forceinline__ void window9(int n, int* ms, bool* dup) {
  int r = n / 56, c = n % 56;
  int rb = r >> 1, cb = c >> 1;
  #pragma unroll
  for (int j = 0; j < 9; j++) {
    int ro = rb + (j/3) - 1; ro = ro < 0 ? 0 : (ro > 27 ? 27 : ro);
    int co = cb + (j%3) - 1; co = co < 0 ? 0 : (co > 27 ? 27 : co);
    ms[j] = ro*28 + co;
  }
  #pragma unroll
  for (int j = 0; j < 9; j++) {
    bool d = false;
    #pragma unroll
    for (int i = 0; i < j; i++) d = d || (ms[i] == ms[j]);
    dup[j] = d;
  }
}

// ---------------- sparse logits + softmax + a_ups + colsum. one wave per (b,n)
__global__ __launch_bounds__(256) void k_attn1(const float* __restrict__ kvb,
                                               const float* __restrict__ qb,
                                               const float* __restrict__ tau,
                                               const float* __restrict__ rpb,
                                               const int* __restrict__ qidx,
                                               float* __restrict__ aups,
                                               float* __restrict__ colsum) {
  int wid = blockIdx.x * 4 + (threadIdx.x >> 6);
  int l = threadIdx.x & 63;
  int b = wid / NIN, n = wid % NIN;
  int ms[9]; bool dup[9];
  window9(n, ms, dup);
  const float* kp = kvb + (size_t)wid * 288;
  float k0 = kp[l];
  float k1 = (l < 32) ? kp[64 + l] : 0.0f;
  int l32 = 64 + (l & 31);
  float et = expf(tau[0]);
  float p[9];
  #pragma unroll
  for (int j = 0; j < 9; j++) {
    const float* qp = qb + (size_t)(b*NOUT + ms[j]) * DIN;
    p[j] = k0 * qp[l] + k1 * qp[l32];
  }
  #pragma unroll
  for (int off = 32; off; off >>= 1)
    #pragma unroll
    for (int j = 0; j < 9; j++) p[j] += __shfl_xor(p[j], off);
  float lg[9];
  #pragma unroll
  for (int j = 0; j < 9; j++)
    lg[j] = dup[j] ? -1e30f : p[j] * et + rpb[qidx[(size_t)n*NOUT + ms[j]]];
  float mx = lg[0];
  #pragma unroll
  for (int j = 1; j < 9; j++) mx = fmaxf(mx, lg[j]);
  float s = 0.f, ex[9];
  #pragma unroll
  for (int j = 0; j < 9; j++) { ex[j] = dup[j] ? 0.f : expf(lg[j] - mx); s += ex[j]; }
  float inv = 1.0f / s;
  #pragma unroll
  for (int j = 0; j < 9; j++) {
    if (l == j && !dup[j]) {
      float a = ex[j] * inv;
      aups[(size_t)wid*NOUT + ms[j]] = a;
      atomicAdd(&colsum[b*NOUT + ms[j]], a);
    }
  }
}

// ---------------- a_down (final iteration only): thread per (b,n)
__global__ __launch_bounds__(256) void k_attn2(const float* __restrict__ aups,
                                               const float* __restrict__ colsum,
                                               float* __restrict__ adown) {
  int id = blockIdx.x * 256 + threadIdx.x;
  int b = id / NIN, n = id % NIN;
  int ms[9]; bool dup[9];
  window9(n, ms, dup);
  #pragma unroll
  for (int j = 0; j < 9; j++) {
    if (!dup[j]) {
      size_t idx = (size_t)id*NOUT + ms[j];
      adown[idx] = aups[idx] / (colsum[b*NOUT + ms[j]] + 1e-8f);
    }
  }
}

// ---------------- updates gather + LN + residual. block = (b, 2x2 slot tile), 192 thr
__global__ __launch_bounds__(192) void k_upd(const float* __restrict__ aups,
                                             const float* __restrict__ colsum,
                                             const float* __restrict__ kvb,
                                             float* __restrict__ xout,
                                             const float* __restrict__ g,
                                             const float* __restrict__ bb) {
  __shared__ float avals[4][64];
  __shared__ float red[4][3][2];
  __shared__ float bc[4][2];
  int b = blockIdx.z;
  int ro0 = blockIdx.y*2, co0 = blockIdx.x*2;
  int r0 = 2*ro0 - 2; if (r0 < 0) r0 = 0;
  int r1 = 2*ro0 + 5; if (r1 > 55) r1 = 55;
  int c0 = 2*co0 - 2; if (c0 < 0) c0 = 0;
  int c1 = 2*co0 + 5; if (c1 > 55) c1 = 55;
  int nr = r1 - r0 + 1, nc = c1 - c0 + 1, cnt = nr*nc;
  int t = threadIdx.x;
  int m0 = ro0*28 + co0, m1 = m0+1, m2 = m0+28, m3 = m0+29;
  if (t < cnt) {
    int ri = t / nc, ci = t % nc;
    int n = (r0 + ri)*56 + (c0 + ci);
    const float* ap = aups + ((size_t)b*NIN + n)*NOUT;
    avals[0][t] = ap[m0]; avals[1][t] = ap[m1];
    avals[2][t] = ap[m2]; avals[3][t] = ap[m3];
  }
  __syncthreads();
  float a0=0.f, a1=0.f, a2=0.f, a3=0.f;
  int i = 0;
  for (int ri = 0; ri < nr; ri++) {
    int nbase = (r0 + ri)*56 + c0;
    for (int ci = 0; ci < nc; ci++, i++) {
      float vv = kvb[((size_t)b*NIN + nbase + ci)*288 + 96 + t];
      a0 += avals[0][i]*vv; a1 += avals[1][i]*vv;
      a2 += avals[2][i]*vv; a3 += avals[3][i]*vv;
    }
  }
  a0 *= 1.0f/(colsum[b*NOUT+m0]+1e-8f);
  a1 *= 1.0f/(colsum[b*NOUT+m1]+1e-8f);
  a2 *= 1.0f/(colsum[b*NOUT+m2]+1e-8f);
  a3 *= 1.0f/(colsum[b*NOUT+m3]+1e-8f);
  float s0=a0,s1=a1,s2=a2,s3=a3, q0=a0*a0,q1=a1*a1,q2=a2*a2,q3=a3*a3;
  #pragma unroll
  for (int off = 32; off; off >>= 1) {
    s0 += __shfl_xor(s0, off); q0 += __shfl_xor(q0, off);
    s1 += __shfl_xor(s1, off); q1 += __shfl_xor(q1, off);
    s2 += __shfl_xor(s2, off); q2 += __shfl_xor(q2, off);
    s3 += __shfl_xor(s3, off); q3 += __shfl_xor(q3, off);
  }
  int w = t >> 6, l = t & 63;
  if (l == 0) {
    red[0][w][0]=s0; red[0][w][1]=q0;
    red[1][w][0]=s1; red[1][w][1]=q1;
    red[2][w][0]=s2; red[2][w][1]=q2;
    red[3][w][0]=s3; red[3][w][1]=q3;
  }
  __syncthreads();
  if (t < 4) {
    float S = red[t][0][0]+red[t][1][0]+red[t][2][0];
    float Q = red[t][0][1]+red[t][1][1]+red[t][2][1];
    float mu = S * (1.0f/192.0f);
    float var = Q * (1.0f/192.0f) - mu*mu;
    bc[t][0] = mu; bc[t][1] = rsqrtf(var + 1e-5f);
  }
  __syncthreads();
  float gt = g[t], bt = bb[t];
  xout[((size_t)b*NOUT+m0)*DOUT + t] += (a0-bc[0][0])*bc[0][1]*gt + bt;
  xout[((size_t)b*NOUT+m1)*DOUT + t] += (a1-bc[1][0])*bc[1][1]*gt + bt;
  xout[((size_t)b*NOUT+m2)*DOUT + t] += (a2-bc[2][0])*bc[2][1]*gt + bt;
  xout[((size_t)b*NOUT+m3)*DOUT + t] += (a3-bc[3][0])*bc[3][1]*gt + bt;
}

// ---------------- MLP + LN + residual. one WAVE per token; 8 tokens x 512 thr; no barriers
__global__ __launch_bounds__(512) void k_mlp(float* __restrict__ xout,
                                             const float* __restrict__ w1_4, const float* __restrict__ b1,
                                             const float* __restrict__ w2_4, const float* __restrict__ b2,
                                             const float* __restrict__ g, const float* __restrict__ bb,
                                             float* __restrict__ dout, int write_out) {
  __shared__ float xt[8][196];
  __shared__ float ht[8][388];
  int tok0 = blockIdx.x * 8;
  int t = threadIdx.x;
  int w = t >> 6, l = t & 63;       // wave w = token w
  const float* ip = xout + (size_t)(tok0 + w)*DOUT;
  #pragma unroll
  for (int jj = 0; jj < 3; jj++) xt[w][l + 64*jj] = ip[l + 64*jj];
  // GEMM1 (wave-private LDS)
  float acc[6];
  #pragma unroll
  for (int j = 0; j < 6; j++) acc[j] = 0.f;
  const float4* w1q = (const float4*)w1_4;
  for (int e4 = 0; e4 < 48; e4++) {
    float4 xv = *(const float4*)&xt[w][e4*4];
    #pragma unroll
    for (int j = 0; j < 6; j++) {
      float4 wv = w1q[(size_t)e4*384 + l + 64*j];
      acc[j] += xv.x*wv.x + xv.y*wv.y + xv.z*wv.z + xv.w*wv.w;
    }
  }
  #pragma unroll
  for (int j = 0; j < 6; j++) {
    int hh = l + 64*j;
    float v = acc[j] + b1[hh];
    v = 0.5f*v*(1.0f + erff(v*0.70710678118f));
    ht[w][hh] = v;
  }
  // GEMM2
  float o2[3] = {0.f, 0.f, 0.f};
  const float4* w2q = (const float4*)w2_4;
  for (int h4 = 0; h4 < 96; h4++) {
    float4 hv = *(const float4*)&ht[w][h4*4];
    #pragma unroll
    for (int j = 0; j < 3; j++) {
      float4 wv = w2q[(size_t)h4*192 + l + 64*j];
      o2[j] += hv.x*wv.x + hv.y*wv.y + hv.z*wv.z + hv.w*wv.w;
    }
  }
  float v[3], s = 0.f, sq = 0.f;
  #pragma unroll
  for (int j = 0; j < 3; j++) {
    v[j] = o2[j] + b2[l + 64*j];
    s += v[j]; sq += v[j]*v[j];
  }
  #pragma unroll
  for (int off = 32; off; off >>= 1) { s += __shfl_xor(s, off); sq += __shfl_xor(sq, off); }
  float mu = s * (1.f/192.f);
  float var = sq * (1.f/192.f) - mu*mu;
  float rs = rsqrtf(var + 1e-5f);
  #pragma unroll
  for (int j = 0; j < 3; j++) {
    int o = l + 64*j;
    float nv = (v[j] - mu)*rs*g[o] + bb[o];
    float nx = xt[w][o] + nv;
    size_t gi = (size_t)(tok0 + w)*DOUT + o;
    xout[gi] = nx;
    if (write_out) dout[gi] = nx;
  }
}

extern "C" void kernel_launch(void* const* d_in, const int* in_sizes, int n_in,
                              void* d_out, int out_size, void* d_ws, size_t ws_size,
                              hipStream_t stream) {
  (void)in_sizes; (void)n_in; (void)ws_size;
  const float* x        = (const float*)d_in[0];
  const float* conv_w   = (const float*)d_in[1];
  const float* q_w      = (const float*)d_in[2];
  const float* k_w      = (const float*)d_in[3];
  const float* v_w      = (const float*)d_in[4];
  const float* mlp_w1   = (const float*)d_in[5];
  const float* mlp_b1   = (const float*)d_in[6];
  const float* mlp_w2   = (const float*)d_in[7];
  const float* mlp_b2   = (const float*)d_in[8];
  const float* ln_in_g  = (const float*)d_in[9];
  const float* ln_in_b  = (const float*)d_in[10];
  const float* ln_out_g = (const float*)d_in[11];
  const float* ln_out_b = (const float*)d_in[12];
  const float* ln_attn_g= (const float*)d_in[13];
  const float* ln_attn_b= (const float*)d_in[14];
  const float* ln_mlp_g = (const float*)d_in[15];
  const float* ln_mlp_b = (const float*)d_in[16];
  const float* tau      = (const float*)d_in[17];
  const float* rpb      = (const float*)d_in[18];
  const int*   qidx     = (const int*)d_in[20];

  float* out = (float*)d_out;
  float* aups  = out + 1204224;       // 8*784*192
  float* adown = out + 20873216;      // + 8*3136*784

  float* ws   = (float*)d_ws;
  float* wct  = ws;                   // 165888
  float* wkv4 = wct + 165888;         // 27648
  float* qw4  = wkv4 + 27648;         // 18432
  float* w1_4 = qw4 + 18432;          // 73728
  float* w2_4 = w1_4 + 73728;         // 73728
  float* xn   = w2_4 + 73728;         // 25088*96
  float* kvb  = xn + (size_t)TOK_IN*DIN;    // 25088*288
  float* xo   = kvb + (size_t)TOK_IN*288;   // 6272*192
  float* qb   = xo + (size_t)TOK_OUT*DOUT;  // 6272*96
  float* cs   = qb + (size_t)TOK_OUT*DIN;   // 6272

  // zero only the sparse attention outputs; x_out region is fully overwritten
  hipMemsetAsync(aups, 0, (size_t)(out_size - 1204224) * sizeof(float), stream);

  k_tr<<<1404, 256, 0, stream>>>(conv_w, k_w, v_w, q_w, mlp_w1, mlp_w2,
                                 wct, wkv4, qw4, w1_4, w2_4);
  k_conv<<<dim3(28, 2, 16), 224, 0, stream>>>(x, wct, xo);
  k_ln<<<TOK_OUT, 64, 0, stream>>>(xo, xo, ln_out_g, ln_out_b, DOUT);   // x_out = LN(seed)
  k_ln<<<TOK_IN, 64, 0, stream>>>(x, xn, ln_in_g, ln_in_b, DIN);        // xn = LN(x)
  k_kv<<<TOK_IN/32, 512, 0, stream>>>(xn, wkv4, kvb);

  for (int it = 0; it < 3; it++) {
    k_q<<<TOK_OUT/8, 256, 0, stream>>>(xo, qw4, ln_out_g, ln_out_b, qb);
    hipMemsetAsync(cs, 0, TOK_OUT * sizeof(float), stream);
    k_attn1<<<TOK_IN/4, 256, 0, stream>>>(kvb, qb, tau, rpb, qidx, aups, cs);
    k_upd<<<dim3(14, 14, NB), 192, 0, stream>>>(aups, cs, kvb, xo, ln_attn_g, ln_attn_b);
    k_mlp<<<TOK_OUT/8, 512, 0, stream>>>(xo, w1_4, mlp_b1, w2_4, mlp_b2,
                                         ln_mlp_g, ln_mlp_b, out, it == 2);
  }
  k_attn2<<<TOK_IN/256, 256, 0, stream>>>(aups, cs, adown);
}

// Round 5
// 902.736 us; speedup vs baseline: 1.1919x; 1.1919x over previous
//
#include <hip/hip_runtime.h>
#include <hip/hip_bf16.h>
#include <math.h>

#define NB 8
#define NIN 3136
#define NOUT 784
#define DIN 96
#define DOUT 192
#define HID 384
#define TOK_IN (NB*NIN)    // 25088
#define TOK_OUT (NB*NOUT)  // 6272

// ---------------- generic LayerNorm over last dim (D<=192), one row per block (64 thr)
__global__ __launch_bounds__(64) void k_ln(const float* __restrict__ in, float* __restrict__ out,
                                           const float* __restrict__ g, const float* __restrict__ bb,
                                           int D) {
  int row = blockIdx.x;
  const float* ip = in + (size_t)row * D;
  float* op = out + (size_t)row * D;
  int t = threadIdx.x;
  float v0 = 0.f, v1 = 0.f, v2 = 0.f, s = 0.f, sq = 0.f;
  if (t < D)       { v0 = ip[t];       s += v0; sq += v0*v0; }
  if (t + 64 < D)  { v1 = ip[t+64];    s += v1; sq += v1*v1; }
  if (t + 128 < D) { v2 = ip[t+128];   s += v2; sq += v2*v2; }
  #pragma unroll
  for (int off = 32; off; off >>= 1) { s += __shfl_xor(s, off); sq += __shfl_xor(sq, off); }
  float mu = s / (float)D;
  float var = sq / (float)D - mu*mu;
  float rs = rsqrtf(var + 1e-5f);
  if (t < D)       op[t]     = (v0-mu)*rs*g[t]     + bb[t];
  if (t + 64 < D)  op[t+64]  = (v1-mu)*rs*g[t+64]  + bb[t+64];
  if (t + 128 < D) op[t+128] = (v2-mu)*rs*g[t+128] + bb[t+128];
}

// ---------------- weight transposes (once per launch)
__global__ void k_tr(const float* __restrict__ cw, const float* __restrict__ kw,
                     const float* __restrict__ vw, const float* __restrict__ qw,
                     const float* __restrict__ w1, const float* __restrict__ w2,
                     float* __restrict__ wct, float* __restrict__ wkv4, float* __restrict__ qw4,
                     float* __restrict__ w1_4, float* __restrict__ w2_4) {
  int i = blockIdx.x * 256 + threadIdx.x;
  if (i < 165888) {                               // wct[kh][kw][ci4][co][q]
    int q = i & 3; int t1 = i >> 2;
    int co = t1 % 192; int t2 = t1 / 192;
    int ci4 = t2 % 24; int t3 = t2 / 24;
    int kwi = t3 % 3; int kh = t3 / 3;
    wct[i] = cw[((co*96 + ci4*4 + q)*3 + kh)*3 + kwi];
  } else if (i < 165888 + 27648) {
    int j = i - 165888; int q = j & 3; int rest = j >> 2;
    int o = rest % 288; int e = (rest / 288)*4 + q;
    wkv4[j] = (o < 96) ? kw[o*96 + e] : vw[(o-96)*96 + e];
  } else if (i < 165888 + 27648 + 18432) {
    int j = i - 165888 - 27648; int q = j & 3; int rest = j >> 2;
    int o = rest % 96; int e = (rest / 96)*4 + q;
    qw4[j] = qw[o*192 + e];
  } else if (i < 165888 + 27648 + 18432 + 73728) {
    int j = i - 165888 - 27648 - 18432; int q = j & 3; int rest = j >> 2;
    int hh = rest % 384; int e = (rest / 384)*4 + q;
    w1_4[j] = w1[hh*192 + e];
  } else if (i < 165888 + 27648 + 18432 + 73728 + 73728) {
    int j = i - 165888 - 27648 - 18432 - 73728; int q = j & 3; int rest = j >> 2;
    int o = rest % 192; int h = (rest / 192)*4 + q;
    w2_4[j] = w2[o*384 + h];
  }
}

// ---------------- strided 3x3 conv seed, LDS-staged implicit GEMM.
__global__ __launch_bounds__(224) void k_conv(const float* __restrict__ x,
                                              const float* __restrict__ wct,
                                              float* __restrict__ seed) {
  __shared__ float xs[3][30][96];   // 34.5 KB
  int ho = blockIdx.x, wh = blockIdx.y;
  int b = blockIdx.z >> 1, half = blockIdx.z & 1;
  int W0 = wh * 14;
  int t = threadIdx.x;
  for (int idx = t; idx < 3*30*96; idx += 224) {
    int ci = idx % 96; int rest = idx / 96;
    int col = rest % 30; int kh = rest / 30;
    int h = 2*ho - 1 + kh;
    int c = 2*W0 - 1 + col;
    float v = 0.f;
    if (h >= 0 && h < 56 && c >= 0 && c < 56)
      v = x[((size_t)b*NIN + h*56 + c)*DIN + ci];
    xs[kh][col][ci] = v;
  }
  __syncthreads();
  int ol = t & 31, tg = t >> 5;       // tg in [0,7)
  int co = half*96 + ol;
  float acc[2][3];
  #pragma unroll
  for (int i = 0; i < 2; i++) { acc[i][0]=0.f; acc[i][1]=0.f; acc[i][2]=0.f; }
  #pragma unroll
  for (int kh = 0; kh < 3; kh++) {
    #pragma unroll
    for (int kwv = 0; kwv < 3; kwv++) {
      #pragma unroll 4
      for (int ci4 = 0; ci4 < 24; ci4++) {
        const float4* wp = (const float4*)wct + (((kh*3 + kwv)*24 + ci4)*192 + co);
        float4 w0 = wp[0], w1 = wp[32], w2 = wp[64];
        float4 x0 = *(const float4*)&xs[kh][4*tg + kwv][ci4*4];
        float4 x1 = *(const float4*)&xs[kh][4*tg + 2 + kwv][ci4*4];
        acc[0][0] += x0.x*w0.x + x0.y*w0.y + x0.z*w0.z + x0.w*w0.w;
        acc[0][1] += x0.x*w1.x + x0.y*w1.y + x0.z*w1.z + x0.w*w1.w;
        acc[0][2] += x0.x*w2.x + x0.y*w2.y + x0.z*w2.z + x0.w*w2.w;
        acc[1][0] += x1.x*w0.x + x1.y*w0.y + x1.z*w0.z + x1.w*w0.w;
        acc[1][1] += x1.x*w1.x + x1.y*w1.y + x1.z*w1.z + x1.w*w1.w;
        acc[1][2] += x1.x*w2.x + x1.y*w2.y + x1.z*w2.z + x1.w*w2.w;
      }
    }
  }
  #pragma unroll
  for (int i = 0; i < 2; i++)
    #pragma unroll
    for (int j = 0; j < 3; j++)
      seed[((size_t)b*NOUT + ho*28 + W0 + 2*tg + i)*DOUT + co + 32*j] = acc[i][j];
}

// ---------------- kv = xn @ [k_w|v_w]^T. 64 tokens/block, 512 thr (16 groups, TM=4, TN=9)
__global__ __launch_bounds__(512) void k_kv(const float* __restrict__ xn,
                                            const float* __restrict__ wkv4,
                                            float* __restrict__ kvb) {
  __shared__ float xt[64][100];
  int tok0 = blockIdx.x * 64;
  int t = threadIdx.x;
  const float4* xp = (const float4*)(xn + (size_t)tok0*DIN);
  for (int i = t; i < 64*24; i += 512) {
    int tok = i / 24, q = i % 24;
    *(float4*)&xt[tok][q*4] = xp[i];
  }
  __syncthreads();
  int ol = t & 31, tg = t >> 5;     // 16 groups x 4 tokens
  float acc[4][9];
  #pragma unroll
  for (int i = 0; i < 4; i++)
    #pragma unroll
    for (int j = 0; j < 9; j++) acc[i][j] = 0.f;
  const float4* wq = (const float4*)wkv4;
  for (int e4 = 0; e4 < 24; e4++) {
    float4 w[9];
    #pragma unroll
    for (int j = 0; j < 9; j++) w[j] = wq[(size_t)e4*288 + ol + 32*j];
    #pragma unroll
    for (int i = 0; i < 4; i++) {
      float4 xv = *(const float4*)&xt[tg*4+i][e4*4];
      #pragma unroll
      for (int j = 0; j < 9; j++)
        acc[i][j] += xv.x*w[j].x + xv.y*w[j].y + xv.z*w[j].z + xv.w*w[j].w;
    }
  }
  #pragma unroll
  for (int i = 0; i < 4; i++)
    #pragma unroll
    for (int j = 0; j < 9; j++)
      kvb[(size_t)(tok0 + tg*4 + i)*288 + ol + 32*j] = acc[i][j];
}

// ---------------- q = LN(x_out) @ q_w^T, LN fused. 16 tokens/block (392 blocks), 256 thr
__global__ __launch_bounds__(256) void k_q(const float* __restrict__ xo,
                                           const float* __restrict__ qw4,
                                           const float* __restrict__ lng, const float* __restrict__ lnb,
                                           float* __restrict__ qb) {
  __shared__ float xt[16][196];
  int tok0 = blockIdx.x * 16;
  int t = threadIdx.x;
  const float4* xp = (const float4*)(xo + (size_t)tok0*DOUT);
  for (int i = t; i < 16*48; i += 256) {
    int tok = i / 48, q = i % 48;
    *(float4*)&xt[tok][q*4] = xp[i];
  }
  __syncthreads();
  // LN: 16 sub-groups of 16 lanes, one token each
  int tok16 = t >> 4, l16 = t & 15;
  float vv[12], s = 0.f, sq = 0.f;
  #pragma unroll
  for (int j = 0; j < 12; j++) {
    float v = xt[tok16][l16 + 16*j];
    vv[j] = v; s += v; sq += v*v;
  }
  #pragma unroll
  for (int off = 8; off; off >>= 1) { s += __shfl_xor(s, off, 16); sq += __shfl_xor(sq, off, 16); }
  float mu = s * (1.f/192.f);
  float var = sq * (1.f/192.f) - mu*mu;
  float rs = rsqrtf(var + 1e-5f);
  #pragma unroll
  for (int j = 0; j < 12; j++) {
    int e = l16 + 16*j;
    xt[tok16][e] = (vv[j]-mu)*rs*lng[e] + lnb[e];
  }
  __syncthreads();
  // GEMM: 8 groups x TM=2 tokens, TN=3
  int ol = t & 31, tg = t >> 5;
  float acc[2][3];
  #pragma unroll
  for (int i = 0; i < 2; i++) { acc[i][0]=0.f; acc[i][1]=0.f; acc[i][2]=0.f; }
  const float4* wq = (const float4*)qw4;
  for (int e4 = 0; e4 < 48; e4++) {
    float4 w0 = wq[(size_t)e4*96 + ol];
    float4 w1 = wq[(size_t)e4*96 + ol + 32];
    float4 w2 = wq[(size_t)e4*96 + ol + 64];
    #pragma unroll
    for (int i = 0; i < 2; i++) {
      float4 xv = *(const float4*)&xt[tg*2+i][e4*4];
      acc[i][0] += xv.x*w0.x + xv.y*w0.y + xv.z*w0.z + xv.w*w0.w;
      acc[i][1] += xv.x*w1.x + xv.y*w1.y + xv.z*w1.z + xv.w*w1.w;
      acc[i][2] += xv.x*w2.x + xv.y*w2.y + xv.z*w2.z + xv.w*w2.w;
    }
  }
  #pragma unroll
  for (int i = 0; i < 2; i++)
    #pragma unroll
    for (int j = 0; j < 3; j++)
      qb[(size_t)(tok0 + tg*2 + i)*DIN + ol + 32*j] = acc[i][j];
}

// ---------------- window helper
__device__ __forceinline__ void window9(int n, int* ms, bool* dup) {
  int r = n / 56, c = n % 56;
  int rb = r >> 1, cb = c >> 1;
  #pragma unroll
  for (int j = 0; j < 9; j++) {
    int ro = rb + (j/3) - 1; ro = ro < 0 ? 0 : (ro > 27 ? 27 : ro);
    int co = cb + (j%3) - 1; co = co < 0 ? 0 : (co > 27 ? 27 : co);
    ms[j] = ro*28 + co;
  }
  #pragma unroll
  for (int j = 0; j < 9; j++) {
    bool d = false;
    #pragma unroll
    for (int i = 0; i < j; i++) d = d || (ms[i] == ms[j]);
    dup[j] = d;
  }
}

// ---------------- sparse logits + softmax + a_ups + colsum. one wave per (b,n)
__global__ __launch_bounds__(256) void k_attn1(const float* __restrict__ kvb,
                                               const float* __restrict__ qb,
                                               const float* __restrict__ tau,
                                               const float* __restrict__ rpb,
                                               const int* __restrict__ qidx,
                                               float* __restrict__ aups,
                                               float* __restrict__ colsum) {
  int wid = blockIdx.x * 4 + (threadIdx.x >> 6);
  int l = threadIdx.x & 63;
  int b = wid / NIN, n = wid % NIN;
  int ms[9]; bool dup[9];
  window9(n, ms, dup);
  const float* kp = kvb + (size_t)wid * 288;
  float k0 = kp[l];
  float k1 = (l < 32) ? kp[64 + l] : 0.0f;
  int l32 = 64 + (l & 31);
  float et = expf(tau[0]);
  float p[9];
  #pragma unroll
  for (int j = 0; j < 9; j++) {
    const float* qp = qb + (size_t)(b*NOUT + ms[j]) * DIN;
    p[j] = k0 * qp[l] + k1 * qp[l32];
  }
  #pragma unroll
  for (int off = 32; off; off >>= 1)
    #pragma unroll
    for (int j = 0; j < 9; j++) p[j] += __shfl_xor(p[j], off);
  float lg[9];
  #pragma unroll
  for (int j = 0; j < 9; j++)
    lg[j] = dup[j] ? -1e30f : p[j] * et + rpb[qidx[(size_t)n*NOUT + ms[j]]];
  float mx = lg[0];
  #pragma unroll
  for (int j = 1; j < 9; j++) mx = fmaxf(mx, lg[j]);
  float s = 0.f, ex[9];
  #pragma unroll
  for (int j = 0; j < 9; j++) { ex[j] = dup[j] ? 0.f : expf(lg[j] - mx); s += ex[j]; }
  float inv = 1.0f / s;
  #pragma unroll
  for (int j = 0; j < 9; j++) {
    if (l == j && !dup[j]) {
      float a = ex[j] * inv;
      aups[(size_t)wid*NOUT + ms[j]] = a;
      atomicAdd(&colsum[b*NOUT + ms[j]], a);
    }
  }
}

// ---------------- a_down (final iteration only): thread per (b,n)
__global__ __launch_bounds__(256) void k_attn2(const float* __restrict__ aups,
                                               const float* __restrict__ colsum,
                                               float* __restrict__ adown) {
  int id = blockIdx.x * 256 + threadIdx.x;
  int b = id / NIN, n = id % NIN;
  int ms[9]; bool dup[9];
  window9(n, ms, dup);
  #pragma unroll
  for (int j = 0; j < 9; j++) {
    if (!dup[j]) {
      size_t idx = (size_t)id*NOUT + ms[j];
      adown[idx] = aups[idx] / (colsum[b*NOUT + ms[j]] + 1e-8f);
    }
  }
}

// ---------------- updates gather + LN + residual. block = (b, 2x2 slot tile), 192 thr
__global__ __launch_bounds__(192) void k_upd(const float* __restrict__ aups,
                                             const float* __restrict__ colsum,
                                             const float* __restrict__ kvb,
                                             float* __restrict__ xout,
                                             const float* __restrict__ g,
                                             const float* __restrict__ bb) {
  __shared__ float avals[4][64];
  __shared__ float red[4][3][2];
  __shared__ float bc[4][2];
  int b = blockIdx.z;
  int ro0 = blockIdx.y*2, co0 = blockIdx.x*2;
  int r0 = 2*ro0 - 2; if (r0 < 0) r0 = 0;
  int r1 = 2*ro0 + 5; if (r1 > 55) r1 = 55;
  int c0 = 2*co0 - 2; if (c0 < 0) c0 = 0;
  int c1 = 2*co0 + 5; if (c1 > 55) c1 = 55;
  int nr = r1 - r0 + 1, nc = c1 - c0 + 1, cnt = nr*nc;
  int t = threadIdx.x;
  int m0 = ro0*28 + co0, m1 = m0+1, m2 = m0+28, m3 = m0+29;
  if (t < cnt) {
    int ri = t / nc, ci = t % nc;
    int n = (r0 + ri)*56 + (c0 + ci);
    const float* ap = aups + ((size_t)b*NIN + n)*NOUT;
    avals[0][t] = ap[m0]; avals[1][t] = ap[m1];
    avals[2][t] = ap[m2]; avals[3][t] = ap[m3];
  }
  __syncthreads();
  float a0=0.f, a1=0.f, a2=0.f, a3=0.f;
  int i = 0;
  for (int ri = 0; ri < nr; ri++) {
    int nbase = (r0 + ri)*56 + c0;
    for (int ci = 0; ci < nc; ci++, i++) {
      float vv = kvb[((size_t)b*NIN + nbase + ci)*288 + 96 + t];
      a0 += avals[0][i]*vv; a1 += avals[1][i]*vv;
      a2 += avals[2][i]*vv; a3 += avals[3][i]*vv;
    }
  }
  a0 *= 1.0f/(colsum[b*NOUT+m0]+1e-8f);
  a1 *= 1.0f/(colsum[b*NOUT+m1]+1e-8f);
  a2 *= 1.0f/(colsum[b*NOUT+m2]+1e-8f);
  a3 *= 1.0f/(colsum[b*NOUT+m3]+1e-8f);
  float s0=a0,s1=a1,s2=a2,s3=a3, q0=a0*a0,q1=a1*a1,q2=a2*a2,q3=a3*a3;
  #pragma unroll
  for (int off = 32; off; off >>= 1) {
    s0 += __shfl_xor(s0, off); q0 += __shfl_xor(q0, off);
    s1 += __shfl_xor(s1, off); q1 += __shfl_xor(q1, off);
    s2 += __shfl_xor(s2, off); q2 += __shfl_xor(q2, off);
    s3 += __shfl_xor(s3, off); q3 += __shfl_xor(q3, off);
  }
  int w = t >> 6, l = t & 63;
  if (l == 0) {
    red[0][w][0]=s0; red[0][w][1]=q0;
    red[1][w][0]=s1; red[1][w][1]=q1;
    red[2][w][0]=s2; red[2][w][1]=q2;
    red[3][w][0]=s3; red[3][w][1]=q3;
  }
  __syncthreads();
  if (t < 4) {
    float S = red[t][0][0]+red[t][1][0]+red[t][2][0];
    float Q = red[t][0][1]+red[t][1][1]+red[t][2][1];
    float mu = S * (1.0f/192.0f);
    float var = Q * (1.0f/192.0f) - mu*mu;
    bc[t][0] = mu; bc[t][1] = rsqrtf(var + 1e-5f);
  }
  __syncthreads();
  float gt = g[t], bt = bb[t];
  xout[((size_t)b*NOUT+m0)*DOUT + t] += (a0-bc[0][0])*bc[0][1]*gt + bt;
  xout[((size_t)b*NOUT+m1)*DOUT + t] += (a1-bc[1][0])*bc[1][1]*gt + bt;
  xout[((size_t)b*NOUT+m2)*DOUT + t] += (a2-bc[2][0])*bc[2][1]*gt + bt;
  xout[((size_t)b*NOUT+m3)*DOUT + t] += (a3-bc[3][0])*bc[3][1]*gt + bt;
}

// ---------------- MLP GEMM1 + GELU -> ht. 64 tokens x 96 hidden per block, TM=8 TN=3
__global__ __launch_bounds__(256) void k_mlp1(const float* __restrict__ xout,
                                              const float* __restrict__ w1_4, const float* __restrict__ b1,
                                              float* __restrict__ ht) {
  __shared__ float xt[64][196];
  int tok0 = blockIdx.x * 64;
  int h0 = blockIdx.y * 96;
  int t = threadIdx.x;
  const float4* xp = (const float4*)(xout + (size_t)tok0*DOUT);
  for (int i = t; i < 64*48; i += 256) {
    int tok = i / 48, q = i % 48;
    *(float4*)&xt[tok][q*4] = xp[i];
  }
  __syncthreads();
  int ol = t & 31, tg = t >> 5;   // 8 groups x 8 tokens
  float acc[8][3];
  #pragma unroll
  for (int i = 0; i < 8; i++) { acc[i][0]=0.f; acc[i][1]=0.f; acc[i][2]=0.f; }
  const float4* wq = (const float4*)w1_4;
  for (int e4 = 0; e4 < 48; e4++) {
    float4 w0 = wq[(size_t)e4*384 + h0 + ol];
    float4 w1v = wq[(size_t)e4*384 + h0 + ol + 32];
    float4 w2v = wq[(size_t)e4*384 + h0 + ol + 64];
    #pragma unroll
    for (int i = 0; i < 8; i++) {
      float4 xv = *(const float4*)&xt[tg*8+i][e4*4];
      acc[i][0] += xv.x*w0.x + xv.y*w0.y + xv.z*w0.z + xv.w*w0.w;
      acc[i][1] += xv.x*w1v.x + xv.y*w1v.y + xv.z*w1v.z + xv.w*w1v.w;
      acc[i][2] += xv.x*w2v.x + xv.y*w2v.y + xv.z*w2v.z + xv.w*w2v.w;
    }
  }
  #pragma unroll
  for (int j = 0; j < 3; j++) {
    int hh = h0 + ol + 32*j;
    float bv = b1[hh];
    #pragma unroll
    for (int i = 0; i < 8; i++) {
      float v = acc[i][j] + bv;
      v = 0.5f*v*(1.0f + erff(v*0.70710678118f));
      ht[(size_t)(tok0 + tg*8 + i)*HID + hh] = v;
    }
  }
}

// ---------------- MLP GEMM2 + LN + residual. 16 tokens/block, TM=2 TN=6
__global__ __launch_bounds__(256) void k_mlp2(float* __restrict__ xout,
                                              const float* __restrict__ ht,
                                              const float* __restrict__ w2_4, const float* __restrict__ b2,
                                              const float* __restrict__ g, const float* __restrict__ bb,
                                              float* __restrict__ dout, int write_out) {
  __shared__ float hs[16][388];
  int tok0 = blockIdx.x * 16;
  int t = threadIdx.x;
  const float4* hp = (const float4*)(ht + (size_t)tok0*HID);
  for (int i = t; i < 16*96; i += 256) {
    int tok = i / 96, q = i % 96;
    *(float4*)&hs[tok][q*4] = hp[i];
  }
  __syncthreads();
  int ol = t & 31, tg = t >> 5;   // 8 groups x 2 tokens
  float acc[2][6];
  #pragma unroll
  for (int i = 0; i < 2; i++)
    #pragma unroll
    for (int j = 0; j < 6; j++) acc[i][j] = 0.f;
  const float4* wq = (const float4*)w2_4;
  for (int h4 = 0; h4 < 96; h4++) {
    float4 w[6];
    #pragma unroll
    for (int j = 0; j < 6; j++) w[j] = wq[(size_t)h4*192 + ol + 32*j];
    #pragma unroll
    for (int i = 0; i < 2; i++) {
      float4 hv = *(const float4*)&hs[tg*2+i][h4*4];
      #pragma unroll
      for (int j = 0; j < 6; j++)
        acc[i][j] += hv.x*w[j].x + hv.y*w[j].y + hv.z*w[j].z + hv.w*w[j].w;
    }
  }
  #pragma unroll
  for (int i = 0; i < 2; i++) {
    int tok = tok0 + tg*2 + i;
    float v[6], s = 0.f, sq = 0.f;
    #pragma unroll
    for (int j = 0; j < 6; j++) {
      v[j] = acc[i][j] + b2[ol + 32*j];
      s += v[j]; sq += v[j]*v[j];
    }
    #pragma unroll
    for (int off = 16; off; off >>= 1) { s += __shfl_xor(s, off, 32); sq += __shfl_xor(sq, off, 32); }
    float mu = s * (1.f/192.f);
    float var = sq * (1.f/192.f) - mu*mu;
    float rs = rsqrtf(var + 1e-5f);
    #pragma unroll
    for (int j = 0; j < 6; j++) {
      int o = ol + 32*j;
      float nv = (v[j] - mu)*rs*g[o] + bb[o];
      size_t gi = (size_t)tok*DOUT + o;
      float nx = xout[gi] + nv;
      xout[gi] = nx;
      if (write_out) dout[gi] = nx;
    }
  }
}

extern "C" void kernel_launch(void* const* d_in, const int* in_sizes, int n_in,
                              void* d_out, int out_size, void* d_ws, size_t ws_size,
                              hipStream_t stream) {
  (void)in_sizes; (void)n_in; (void)ws_size;
  const float* x        = (const float*)d_in[0];
  const float* conv_w   = (const float*)d_in[1];
  const float* q_w      = (const float*)d_in[2];
  const float* k_w      = (const float*)d_in[3];
  const float* v_w      = (const float*)d_in[4];
  const float* mlp_w1   = (const float*)d_in[5];
  const float* mlp_b1   = (const float*)d_in[6];
  const float* mlp_w2   = (const float*)d_in[7];
  const float* mlp_b2   = (const float*)d_in[8];
  const float* ln_in_g  = (const float*)d_in[9];
  const float* ln_in_b  = (const float*)d_in[10];
  const float* ln_out_g = (const float*)d_in[11];
  const float* ln_out_b = (const float*)d_in[12];
  const float* ln_attn_g= (const float*)d_in[13];
  const float* ln_attn_b= (const float*)d_in[14];
  const float* ln_mlp_g = (const float*)d_in[15];
  const float* ln_mlp_b = (const float*)d_in[16];
  const float* tau      = (const float*)d_in[17];
  const float* rpb      = (const float*)d_in[18];
  const int*   qidx     = (const int*)d_in[20];

  float* out = (float*)d_out;
  float* aups  = out + 1204224;       // 8*784*192
  float* adown = out + 20873216;      // + 8*3136*784

  float* ws   = (float*)d_ws;
  float* wct  = ws;                   // 165888
  float* wkv4 = wct + 165888;         // 27648
  float* qw4  = wkv4 + 27648;         // 18432
  float* w1_4 = qw4 + 18432;          // 73728
  float* w2_4 = w1_4 + 73728;         // 73728
  float* xn   = w2_4 + 73728;         // 25088*96
  float* kvb  = xn + (size_t)TOK_IN*DIN;    // 25088*288
  float* xo   = kvb + (size_t)TOK_IN*288;   // 6272*192
  float* qb   = xo + (size_t)TOK_OUT*DOUT;  // 6272*96
  float* htb  = qb + (size_t)TOK_OUT*DIN;   // 6272*384
  float* cs   = htb + (size_t)TOK_OUT*HID;  // 6272

  // zero only the sparse attention outputs; x_out region is fully overwritten
  hipMemsetAsync(aups, 0, (size_t)(out_size - 1204224) * sizeof(float), stream);

  k_tr<<<1404, 256, 0, stream>>>(conv_w, k_w, v_w, q_w, mlp_w1, mlp_w2,
                                 wct, wkv4, qw4, w1_4, w2_4);
  k_conv<<<dim3(28, 2, 16), 224, 0, stream>>>(x, wct, xo);
  k_ln<<<TOK_OUT, 64, 0, stream>>>(xo, xo, ln_out_g, ln_out_b, DOUT);   // x_out = LN(seed)
  k_ln<<<TOK_IN, 64, 0, stream>>>(x, xn, ln_in_g, ln_in_b, DIN);        // xn = LN(x)
  k_kv<<<TOK_IN/64, 512, 0, stream>>>(xn, wkv4, kvb);

  for (int it = 0; it < 3; it++) {
    k_q<<<TOK_OUT/16, 256, 0, stream>>>(xo, qw4, ln_out_g, ln_out_b, qb);
    hipMemsetAsync(cs, 0, TOK_OUT * sizeof(float), stream);
    k_attn1<<<TOK_IN/4, 256, 0, stream>>>(kvb, qb, tau, rpb, qidx, aups, cs);
    k_upd<<<dim3(14, 14, NB), 192, 0, stream>>>(aups, cs, kvb, xo, ln_attn_g, ln_attn_b);
    k_mlp1<<<dim3(TOK_OUT/64, 4), 256, 0, stream>>>(xo, w1_4, mlp_b1, htb);
    k_mlp2<<<TOK_OUT/16, 256, 0, stream>>>(xo, htb, w2_4, mlp_b2,
                                           ln_mlp_g, ln_mlp_b, out, it == 2);
  }
  k_attn2<<<TOK_IN/256, 256, 0, stream>>>(aups, cs, adown);
}

// Round 6
// 877.860 us; speedup vs baseline: 1.2257x; 1.0283x over previous
//
#include <hip/hip_runtime.h>
#include <hip/hip_bf16.h>
#include <math.h>

#define NB 8
#define NIN 3136
#define NOUT 784
#define DIN 96
#define DOUT 192
#define HID 384
#define TOK_IN (NB*NIN)    // 25088
#define TOK_OUT (NB*NOUT)  // 6272

// ---------------- LayerNorm over last dim (used once, for seed), one row per block (64 thr)
__global__ __launch_bounds__(64) void k_ln(const float* __restrict__ in, float* __restrict__ out,
                                           const float* __restrict__ g, const float* __restrict__ bb,
                                           int D) {
  int row = blockIdx.x;
  const float* ip = in + (size_t)row * D;
  float* op = out + (size_t)row * D;
  int t = threadIdx.x;
  float v0 = 0.f, v1 = 0.f, v2 = 0.f, s = 0.f, sq = 0.f;
  if (t < D)       { v0 = ip[t];       s += v0; sq += v0*v0; }
  if (t + 64 < D)  { v1 = ip[t+64];    s += v1; sq += v1*v1; }
  if (t + 128 < D) { v2 = ip[t+128];   s += v2; sq += v2*v2; }
  #pragma unroll
  for (int off = 32; off; off >>= 1) { s += __shfl_xor(s, off); sq += __shfl_xor(sq, off); }
  float mu = s / (float)D;
  float var = sq / (float)D - mu*mu;
  float rs = rsqrtf(var + 1e-5f);
  if (t < D)       op[t]     = (v0-mu)*rs*g[t]     + bb[t];
  if (t + 64 < D)  op[t+64]  = (v1-mu)*rs*g[t+64]  + bb[t+64];
  if (t + 128 < D) op[t+128] = (v2-mu)*rs*g[t+128] + bb[t+128];
}

// ---------------- weight transposes (once per launch)
__global__ void k_tr(const float* __restrict__ cw, const float* __restrict__ kw,
                     const float* __restrict__ vw, const float* __restrict__ qw,
                     const float* __restrict__ w1, const float* __restrict__ w2,
                     float* __restrict__ wct, float* __restrict__ wkv4, float* __restrict__ qw4,
                     float* __restrict__ w1_4, float* __restrict__ w2_4) {
  int i = blockIdx.x * 256 + threadIdx.x;
  if (i < 165888) {                               // wct[kh][kw][ci4][co][q]
    int q = i & 3; int t1 = i >> 2;
    int co = t1 % 192; int t2 = t1 / 192;
    int ci4 = t2 % 24; int t3 = t2 / 24;
    int kwi = t3 % 3; int kh = t3 / 3;
    wct[i] = cw[((co*96 + ci4*4 + q)*3 + kh)*3 + kwi];
  } else if (i < 165888 + 27648) {
    int j = i - 165888; int q = j & 3; int rest = j >> 2;
    int o = rest % 288; int e = (rest / 288)*4 + q;
    wkv4[j] = (o < 96) ? kw[o*96 + e] : vw[(o-96)*96 + e];
  } else if (i < 165888 + 27648 + 18432) {
    int j = i - 165888 - 27648; int q = j & 3; int rest = j >> 2;
    int o = rest % 96; int e = (rest / 96)*4 + q;
    qw4[j] = qw[o*192 + e];
  } else if (i < 165888 + 27648 + 18432 + 73728) {
    int j = i - 165888 - 27648 - 18432; int q = j & 3; int rest = j >> 2;
    int hh = rest % 384; int e = (rest / 384)*4 + q;
    w1_4[j] = w1[hh*192 + e];
  } else if (i < 165888 + 27648 + 18432 + 73728 + 73728) {
    int j = i - 165888 - 27648 - 18432 - 73728; int q = j & 3; int rest = j >> 2;
    int o = rest % 192; int h = (rest / 192)*4 + q;
    w2_4[j] = w2[o*384 + h];
  }
}

// ---------------- strided 3x3 conv seed. grid (28 ho, 2 half, 8 b), 224 thr = 7 grp x 32.
// group tg: wo = 4tg+{0..3}; lane ol: co = half*96 + ol + 32j (j<3). TM=4, TN=3.
__global__ __launch_bounds__(224) void k_conv(const float* __restrict__ x,
                                              const float* __restrict__ wct,
                                              float* __restrict__ seed) {
  __shared__ float xs[3][58][96];   // 66.8 KB: full-row halo tile
  int ho = blockIdx.x, half = blockIdx.y, b = blockIdx.z;
  int t = threadIdx.x;
  for (int i = t; i < 3*58*24; i += 224) {
    int q = i % 24; int rest = i / 24;
    int col = rest % 58; int kh = rest / 58;
    int h = 2*ho - 1 + kh;
    int c = col - 1;
    float4 v = make_float4(0.f,0.f,0.f,0.f);
    if (h >= 0 && h < 56 && c >= 0 && c < 56)
      v = *(const float4*)(x + ((size_t)b*NIN + h*56 + c)*DIN + q*4);
    *(float4*)&xs[kh][col][q*4] = v;
  }
  __syncthreads();
  int ol = t & 31, tg = t >> 5;       // tg in [0,7)
  int co = half*96 + ol;
  float acc[4][3];
  #pragma unroll
  for (int i = 0; i < 4; i++) { acc[i][0]=0.f; acc[i][1]=0.f; acc[i][2]=0.f; }
  #pragma unroll
  for (int kh = 0; kh < 3; kh++) {
    #pragma unroll 2
    for (int ci4 = 0; ci4 < 24; ci4++) {
      float4 xr[9];
      #pragma unroll
      for (int c = 0; c < 9; c++) xr[c] = *(const float4*)&xs[kh][8*tg + c][ci4*4];
      #pragma unroll
      for (int kwv = 0; kwv < 3; kwv++) {
        const float4* wp = (const float4*)wct + (((kh*3 + kwv)*24 + ci4)*192 + co);
        float4 w0 = wp[0], w1 = wp[32], w2 = wp[64];
        #pragma unroll
        for (int i = 0; i < 4; i++) {
          float4 xv = xr[2*i + kwv];
          acc[i][0] += xv.x*w0.x + xv.y*w0.y + xv.z*w0.z + xv.w*w0.w;
          acc[i][1] += xv.x*w1.x + xv.y*w1.y + xv.z*w1.z + xv.w*w1.w;
          acc[i][2] += xv.x*w2.x + xv.y*w2.y + xv.z*w2.z + xv.w*w2.w;
        }
      }
    }
  }
  #pragma unroll
  for (int i = 0; i < 4; i++)
    #pragma unroll
    for (int j = 0; j < 3; j++)
      seed[((size_t)b*NOUT + ho*28 + 4*tg + i)*DOUT + co + 32*j] = acc[i][j];
}

// ---------------- kv = LN(x) @ [k_w|v_w]^T, LN fused. 64 tokens/block, 512 thr
__global__ __launch_bounds__(512) void k_kv(const float* __restrict__ x,
                                            const float* __restrict__ wkv4,
                                            const float* __restrict__ lng, const float* __restrict__ lnb,
                                            float* __restrict__ kvb) {
  __shared__ float xt[64][100];
  int tok0 = blockIdx.x * 64;
  int t = threadIdx.x;
  const float4* xp = (const float4*)(x + (size_t)tok0*DIN);
  for (int i = t; i < 64*24; i += 512) {
    int tok = i / 24, q = i % 24;
    *(float4*)&xt[tok][q*4] = xp[i];
  }
  __syncthreads();
  // LN: 8-lane subgroup per token
  int tok8 = t >> 3, l8 = t & 7;
  float vv[12], s = 0.f, sq = 0.f;
  #pragma unroll
  for (int j = 0; j < 12; j++) {
    float v = xt[tok8][l8 + 8*j];
    vv[j] = v; s += v; sq += v*v;
  }
  #pragma unroll
  for (int off = 4; off; off >>= 1) { s += __shfl_xor(s, off, 8); sq += __shfl_xor(sq, off, 8); }
  float mu = s * (1.f/96.f);
  float var = sq * (1.f/96.f) - mu*mu;
  float rs = rsqrtf(var + 1e-5f);
  #pragma unroll
  for (int j = 0; j < 12; j++) {
    int e = l8 + 8*j;
    xt[tok8][e] = (vv[j]-mu)*rs*lng[e] + lnb[e];
  }
  __syncthreads();
  int ol = t & 31, tg = t >> 5;     // 16 groups x 4 tokens
  float acc[4][9];
  #pragma unroll
  for (int i = 0; i < 4; i++)
    #pragma unroll
    for (int j = 0; j < 9; j++) acc[i][j] = 0.f;
  const float4* wq = (const float4*)wkv4;
  for (int e4 = 0; e4 < 24; e4++) {
    float4 w[9];
    #pragma unroll
    for (int j = 0; j < 9; j++) w[j] = wq[(size_t)e4*288 + ol + 32*j];
    #pragma unroll
    for (int i = 0; i < 4; i++) {
      float4 xv = *(const float4*)&xt[tg*4+i][e4*4];
      #pragma unroll
      for (int j = 0; j < 9; j++)
        acc[i][j] += xv.x*w[j].x + xv.y*w[j].y + xv.z*w[j].z + xv.w*w[j].w;
    }
  }
  #pragma unroll
  for (int i = 0; i < 4; i++)
    #pragma unroll
    for (int j = 0; j < 9; j++)
      kvb[(size_t)(tok0 + tg*4 + i)*288 + ol + 32*j] = acc[i][j];
}

// ---------------- q = LN(x_out) @ q_w^T, LN fused; also zeroes colsum slice. 16 tok/block
__global__ __launch_bounds__(256) void k_q(const float* __restrict__ xo,
                                           const float* __restrict__ qw4,
                                           const float* __restrict__ lng, const float* __restrict__ lnb,
                                           float* __restrict__ qb, float* __restrict__ cs) {
  __shared__ float xt[16][196];
  int tok0 = blockIdx.x * 16;
  int t = threadIdx.x;
  if (t < 16) cs[tok0 + t] = 0.f;     // zero colsum for this block's tokens
  const float4* xp = (const float4*)(xo + (size_t)tok0*DOUT);
  for (int i = t; i < 16*48; i += 256) {
    int tok = i / 48, q = i % 48;
    *(float4*)&xt[tok][q*4] = xp[i];
  }
  __syncthreads();
  int tok16 = t >> 4, l16 = t & 15;
  float vv[12], s = 0.f, sq = 0.f;
  #pragma unroll
  for (int j = 0; j < 12; j++) {
    float v = xt[tok16][l16 + 16*j];
    vv[j] = v; s += v; sq += v*v;
  }
  #pragma unroll
  for (int off = 8; off; off >>= 1) { s += __shfl_xor(s, off, 16); sq += __shfl_xor(sq, off, 16); }
  float mu = s * (1.f/192.f);
  float var = sq * (1.f/192.f) - mu*mu;
  float rs = rsqrtf(var + 1e-5f);
  #pragma unroll
  for (int j = 0; j < 12; j++) {
    int e = l16 + 16*j;
    xt[tok16][e] = (vv[j]-mu)*rs*lng[e] + lnb[e];
  }
  __syncthreads();
  int ol = t & 31, tg = t >> 5;
  float acc[2][3];
  #pragma unroll
  for (int i = 0; i < 2; i++) { acc[i][0]=0.f; acc[i][1]=0.f; acc[i][2]=0.f; }
  const float4* wq = (const float4*)qw4;
  for (int e4 = 0; e4 < 48; e4++) {
    float4 w0 = wq[(size_t)e4*96 + ol];
    float4 w1 = wq[(size_t)e4*96 + ol + 32];
    float4 w2 = wq[(size_t)e4*96 + ol + 64];
    #pragma unroll
    for (int i = 0; i < 2; i++) {
      float4 xv = *(const float4*)&xt[tg*2+i][e4*4];
      acc[i][0] += xv.x*w0.x + xv.y*w0.y + xv.z*w0.z + xv.w*w0.w;
      acc[i][1] += xv.x*w1.x + xv.y*w1.y + xv.z*w1.z + xv.w*w1.w;
      acc[i][2] += xv.x*w2.x + xv.y*w2.y + xv.z*w2.z + xv.w*w2.w;
    }
  }
  #pragma unroll
  for (int i = 0; i < 2; i++)
    #pragma unroll
    for (int j = 0; j < 3; j++)
      qb[(size_t)(tok0 + tg*2 + i)*DIN + ol + 32*j] = acc[i][j];
}

// ---------------- window helper
__device__ __forceinline__ void window9(int n, int* ms, bool* dup) {
  int r = n / 56, c = n % 56;
  int rb = r >> 1, cb = c >> 1;
  #pragma unroll
  for (int j = 0; j < 9; j++) {
    int ro = rb + (j/3) - 1; ro = ro < 0 ? 0 : (ro > 27 ? 27 : ro);
    int co = cb + (j%3) - 1; co = co < 0 ? 0 : (co > 27 ? 27 : co);
    ms[j] = ro*28 + co;
  }
  #pragma unroll
  for (int j = 0; j < 9; j++) {
    bool d = false;
    #pragma unroll
    for (int i = 0; i < j; i++) d = d || (ms[i] == ms[j]);
    dup[j] = d;
  }
}

// ---------------- sparse logits + softmax + a_ups + colsum. one wave per (b,n)
__global__ __launch_bounds__(256) void k_attn1(const float* __restrict__ kvb,
                                               const float* __restrict__ qb,
                                               const float* __restrict__ tau,
                                               const float* __restrict__ rpb,
                                               const int* __restrict__ qidx,
                                               float* __restrict__ aups,
                                               float* __restrict__ colsum) {
  int wid = blockIdx.x * 4 + (threadIdx.x >> 6);
  int l = threadIdx.x & 63;
  int b = wid / NIN, n = wid % NIN;
  int ms[9]; bool dup[9];
  window9(n, ms, dup);
  const float* kp = kvb + (size_t)wid * 288;
  float k0 = kp[l];
  float k1 = (l < 32) ? kp[64 + l] : 0.0f;
  int l32 = 64 + (l & 31);
  float et = expf(tau[0]);
  float p[9];
  #pragma unroll
  for (int j = 0; j < 9; j++) {
    const float* qp = qb + (size_t)(b*NOUT + ms[j]) * DIN;
    p[j] = k0 * qp[l] + k1 * qp[l32];
  }
  #pragma unroll
  for (int off = 32; off; off >>= 1)
    #pragma unroll
    for (int j = 0; j < 9; j++) p[j] += __shfl_xor(p[j], off);
  float lg[9];
  #pragma unroll
  for (int j = 0; j < 9; j++)
    lg[j] = dup[j] ? -1e30f : p[j] * et + rpb[qidx[(size_t)n*NOUT + ms[j]]];
  float mx = lg[0];
  #pragma unroll
  for (int j = 1; j < 9; j++) mx = fmaxf(mx, lg[j]);
  float s = 0.f, ex[9];
  #pragma unroll
  for (int j = 0; j < 9; j++) { ex[j] = dup[j] ? 0.f : expf(lg[j] - mx); s += ex[j]; }
  float inv = 1.0f / s;
  #pragma unroll
  for (int j = 0; j < 9; j++) {
    if (l == j && !dup[j]) {
      float a = ex[j] * inv;
      aups[(size_t)wid*NOUT + ms[j]] = a;
      atomicAdd(&colsum[b*NOUT + ms[j]], a);
    }
  }
}

// ---------------- updates gather + LN + residual (+ fused a_down on last iter)
__global__ __launch_bounds__(192) void k_upd(const float* __restrict__ aups,
                                             const float* __restrict__ colsum,
                                             const float* __restrict__ kvb,
                                             float* __restrict__ xout,
                                             const float* __restrict__ g,
                                             const float* __restrict__ bb,
                                             float* __restrict__ adown, int wadown) {
  __shared__ float avals[4][64];
  __shared__ float red[4][3][2];
  __shared__ float bc[4][2];
  int b = blockIdx.z;
  int ro0 = blockIdx.y*2, co0 = blockIdx.x*2;
  int r0 = 2*ro0 - 2; if (r0 < 0) r0 = 0;
  int r1 = 2*ro0 + 5; if (r1 > 55) r1 = 55;
  int c0 = 2*co0 - 2; if (c0 < 0) c0 = 0;
  int c1 = 2*co0 + 5; if (c1 > 55) c1 = 55;
  int nr = r1 - r0 + 1, nc = c1 - c0 + 1, cnt = nr*nc;
  int t = threadIdx.x;
  int m0 = ro0*28 + co0, m1 = m0+1, m2 = m0+28, m3 = m0+29;
  if (t < cnt) {
    int ri = t / nc, ci = t % nc;
    int n = (r0 + ri)*56 + (c0 + ci);
    const float* ap = aups + ((size_t)b*NIN + n)*NOUT;
    avals[0][t] = ap[m0]; avals[1][t] = ap[m1];
    avals[2][t] = ap[m2]; avals[3][t] = ap[m3];
  }
  __syncthreads();
  float a0=0.f, a1=0.f, a2=0.f, a3=0.f;
  int i = 0;
  for (int ri = 0; ri < nr; ri++) {
    int nbase = (r0 + ri)*56 + c0;
    for (int ci = 0; ci < nc; ci++, i++) {
      float vv = kvb[((size_t)b*NIN + nbase + ci)*288 + 96 + t];
      a0 += avals[0][i]*vv; a1 += avals[1][i]*vv;
      a2 += avals[2][i]*vv; a3 += avals[3][i]*vv;
    }
  }
  float inv0 = 1.0f/(colsum[b*NOUT+m0]+1e-8f);
  float inv1 = 1.0f/(colsum[b*NOUT+m1]+1e-8f);
  float inv2 = 1.0f/(colsum[b*NOUT+m2]+1e-8f);
  float inv3 = 1.0f/(colsum[b*NOUT+m3]+1e-8f);
  if (wadown && t < cnt) {
    int ri = t / nc, ci = t % nc;
    int n = (r0 + ri)*56 + (c0 + ci);
    float* dp = adown + ((size_t)b*NIN + n)*NOUT;
    dp[m0] = avals[0][t]*inv0; dp[m1] = avals[1][t]*inv1;
    dp[m2] = avals[2][t]*inv2; dp[m3] = avals[3][t]*inv3;
  }
  a0 *= inv0; a1 *= inv1; a2 *= inv2; a3 *= inv3;
  float s0=a0,s1=a1,s2=a2,s3=a3, q0=a0*a0,q1=a1*a1,q2=a2*a2,q3=a3*a3;
  #pragma unroll
  for (int off = 32; off; off >>= 1) {
    s0 += __shfl_xor(s0, off); q0 += __shfl_xor(q0, off);
    s1 += __shfl_xor(s1, off); q1 += __shfl_xor(q1, off);
    s2 += __shfl_xor(s2, off); q2 += __shfl_xor(q2, off);
    s3 += __shfl_xor(s3, off); q3 += __shfl_xor(q3, off);
  }
  int w = t >> 6, l = t & 63;
  if (l == 0) {
    red[0][w][0]=s0; red[0][w][1]=q0;
    red[1][w][0]=s1; red[1][w][1]=q1;
    red[2][w][0]=s2; red[2][w][1]=q2;
    red[3][w][0]=s3; red[3][w][1]=q3;
  }
  __syncthreads();
  if (t < 4) {
    float S = red[t][0][0]+red[t][1][0]+red[t][2][0];
    float Q = red[t][0][1]+red[t][1][1]+red[t][2][1];
    float mu = S * (1.0f/192.0f);
    float var = Q * (1.0f/192.0f) - mu*mu;
    bc[t][0] = mu; bc[t][1] = rsqrtf(var + 1e-5f);
  }
  __syncthreads();
  float gt = g[t], bt = bb[t];
  xout[((size_t)b*NOUT+m0)*DOUT + t] += (a0-bc[0][0])*bc[0][1]*gt + bt;
  xout[((size_t)b*NOUT+m1)*DOUT + t] += (a1-bc[1][0])*bc[1][1]*gt + bt;
  xout[((size_t)b*NOUT+m2)*DOUT + t] += (a2-bc[2][0])*bc[2][1]*gt + bt;
  xout[((size_t)b*NOUT+m3)*DOUT + t] += (a3-bc[3][0])*bc[3][1]*gt + bt;
}

// ---------------- MLP GEMM1 + GELU -> ht. 64 tokens x 96 hidden per block, TM=8 TN=3
__global__ __launch_bounds__(256) void k_mlp1(const float* __restrict__ xout,
                                              const float* __restrict__ w1_4, const float* __restrict__ b1,
                                              float* __restrict__ ht) {
  __shared__ float xt[64][196];
  int tok0 = blockIdx.x * 64;
  int h0 = blockIdx.y * 96;
  int t = threadIdx.x;
  const float4* xp = (const float4*)(xout + (size_t)tok0*DOUT);
  for (int i = t; i < 64*48; i += 256) {
    int tok = i / 48, q = i % 48;
    *(float4*)&xt[tok][q*4] = xp[i];
  }
  __syncthreads();
  int ol = t & 31, tg = t >> 5;   // 8 groups x 8 tokens
  float acc[8][3];
  #pragma unroll
  for (int i = 0; i < 8; i++) { acc[i][0]=0.f; acc[i][1]=0.f; acc[i][2]=0.f; }
  const float4* wq = (const float4*)w1_4;
  for (int e4 = 0; e4 < 48; e4++) {
    float4 w0 = wq[(size_t)e4*384 + h0 + ol];
    float4 w1v = wq[(size_t)e4*384 + h0 + ol + 32];
    float4 w2v = wq[(size_t)e4*384 + h0 + ol + 64];
    #pragma unroll
    for (int i = 0; i < 8; i++) {
      float4 xv = *(const float4*)&xt[tg*8+i][e4*4];
      acc[i][0] += xv.x*w0.x + xv.y*w0.y + xv.z*w0.z + xv.w*w0.w;
      acc[i][1] += xv.x*w1v.x + xv.y*w1v.y + xv.z*w1v.z + xv.w*w1v.w;
      acc[i][2] += xv.x*w2v.x + xv.y*w2v.y + xv.z*w2v.z + xv.w*w2v.w;
    }
  }
  #pragma unroll
  for (int j = 0; j < 3; j++) {
    int hh = h0 + ol + 32*j;
    float bv = b1[hh];
    #pragma unroll
    for (int i = 0; i < 8; i++) {
      float v = acc[i][j] + bv;
      v = 0.5f*v*(1.0f + erff(v*0.70710678118f));
      ht[(size_t)(tok0 + tg*8 + i)*HID + hh] = v;
    }
  }
}

// ---------------- MLP GEMM2 + LN + residual. 16 tokens/block, TM=2 TN=6
__global__ __launch_bounds__(256) void k_mlp2(float* __restrict__ xout,
                                              const float* __restrict__ ht,
                                              const float* __restrict__ w2_4, const float* __restrict__ b2,
                                              const float* __restrict__ g, const float* __restrict__ bb,
                                              float* __restrict__ dout, int write_out) {
  __shared__ float hs[16][388];
  int tok0 = blockIdx.x * 16;
  int t = threadIdx.x;
  const float4* hp = (const float4*)(ht + (size_t)tok0*HID);
  for (int i = t; i < 16*96; i += 256) {
    int tok = i / 96, q = i % 96;
    *(float4*)&hs[tok][q*4] = hp[i];
  }
  __syncthreads();
  int ol = t & 31, tg = t >> 5;   // 8 groups x 2 tokens
  float acc[2][6];
  #pragma unroll
  for (int i = 0; i < 2; i++)
    #pragma unroll
    for (int j = 0; j < 6; j++) acc[i][j] = 0.f;
  const float4* wq = (const float4*)w2_4;
  for (int h4 = 0; h4 < 96; h4++) {
    float4 w[6];
    #pragma unroll
    for (int j = 0; j < 6; j++) w[j] = wq[(size_t)h4*192 + ol + 32*j];
    #pragma unroll
    for (int i = 0; i < 2; i++) {
      float4 hv = *(const float4*)&hs[tg*2+i][h4*4];
      #pragma unroll
      for (int j = 0; j < 6; j++)
        acc[i][j] += hv.x*w[j].x + hv.y*w[j].y + hv.z*w[j].z + hv.w*w[j].w;
    }
  }
  #pragma unroll
  for (int i = 0; i < 2; i++) {
    int tok = tok0 + tg*2 + i;
    float v[6], s = 0.f, sq = 0.f;
    #pragma unroll
    for (int j = 0; j < 6; j++) {
      v[j] = acc[i][j] + b2[ol + 32*j];
      s += v[j]; sq += v[j]*v[j];
    }
    #pragma unroll
    for (int off = 16; off; off >>= 1) { s += __shfl_xor(s, off, 32); sq += __shfl_xor(sq, off, 32); }
    float mu = s * (1.f/192.f);
    float var = sq * (1.f/192.f) - mu*mu;
    float rs = rsqrtf(var + 1e-5f);
    #pragma unroll
    for (int j = 0; j < 6; j++) {
      int o = ol + 32*j;
      float nv = (v[j] - mu)*rs*g[o] + bb[o];
      size_t gi = (size_t)tok*DOUT + o;
      float nx = xout[gi] + nv;
      xout[gi] = nx;
      if (write_out) dout[gi] = nx;
    }
  }
}

extern "C" void kernel_launch(void* const* d_in, const int* in_sizes, int n_in,
                              void* d_out, int out_size, void* d_ws, size_t ws_size,
                              hipStream_t stream) {
  (void)in_sizes; (void)n_in; (void)ws_size;
  const float* x        = (const float*)d_in[0];
  const float* conv_w   = (const float*)d_in[1];
  const float* q_w      = (const float*)d_in[2];
  const float* k_w      = (const float*)d_in[3];
  const float* v_w      = (const float*)d_in[4];
  const float* mlp_w1   = (const float*)d_in[5];
  const float* mlp_b1   = (const float*)d_in[6];
  const float* mlp_w2   = (const float*)d_in[7];
  const float* mlp_b2   = (const float*)d_in[8];
  const float* ln_in_g  = (const float*)d_in[9];
  const float* ln_in_b  = (const float*)d_in[10];
  const float* ln_out_g = (const float*)d_in[11];
  const float* ln_out_b = (const float*)d_in[12];
  const float* ln_attn_g= (const float*)d_in[13];
  const float* ln_attn_b= (const float*)d_in[14];
  const float* ln_mlp_g = (const float*)d_in[15];
  const float* ln_mlp_b = (const float*)d_in[16];
  const float* tau      = (const float*)d_in[17];
  const float* rpb      = (const float*)d_in[18];
  const int*   qidx     = (const int*)d_in[20];

  float* out = (float*)d_out;
  float* aups  = out + 1204224;       // 8*784*192
  float* adown = out + 20873216;      // + 8*3136*784

  float* ws   = (float*)d_ws;
  float* wct  = ws;                   // 165888
  float* wkv4 = wct + 165888;         // 27648
  float* qw4  = wkv4 + 27648;         // 18432
  float* w1_4 = qw4 + 18432;          // 73728
  float* w2_4 = w1_4 + 73728;         // 73728
  float* kvb  = w2_4 + 73728;         // 25088*288
  float* xo   = kvb + (size_t)TOK_IN*288;   // 6272*192
  float* qb   = xo + (size_t)TOK_OUT*DOUT;  // 6272*96
  float* htb  = qb + (size_t)TOK_OUT*DIN;   // 6272*384
  float* cs   = htb + (size_t)TOK_OUT*HID;  // 6272

  // zero only the sparse attention outputs; x_out region is fully overwritten
  hipMemsetAsync(aups, 0, (size_t)(out_size - 1204224) * sizeof(float), stream);

  k_tr<<<1404, 256, 0, stream>>>(conv_w, k_w, v_w, q_w, mlp_w1, mlp_w2,
                                 wct, wkv4, qw4, w1_4, w2_4);
  k_conv<<<dim3(28, 2, 8), 224, 0, stream>>>(x, wct, xo);
  k_ln<<<TOK_OUT, 64, 0, stream>>>(xo, xo, ln_out_g, ln_out_b, DOUT);   // x_out = LN(seed)
  k_kv<<<TOK_IN/64, 512, 0, stream>>>(x, wkv4, ln_in_g, ln_in_b, kvb);

  for (int it = 0; it < 3; it++) {
    k_q<<<TOK_OUT/16, 256, 0, stream>>>(xo, qw4, ln_out_g, ln_out_b, qb, cs);
    k_attn1<<<TOK_IN/4, 256, 0, stream>>>(kvb, qb, tau, rpb, qidx, aups, cs);
    k_upd<<<dim3(14, 14, NB), 192, 0, stream>>>(aups, cs, kvb, xo, ln_attn_g, ln_attn_b,
                                                adown, it == 2);
    k_mlp1<<<dim3(TOK_OUT/64, 4), 256, 0, stream>>>(xo, w1_4, mlp_b1, htb);
    k_mlp2<<<TOK_OUT/16, 256, 0, stream>>>(xo, htb, w2_4, mlp_b2,
                                           ln_mlp_g, ln_mlp_b, out, it == 2);
  }
}

// Round 7
// 853.326 us; speedup vs baseline: 1.2610x; 1.0288x over previous
//
#include <hip/hip_runtime.h>
#include <hip/hip_bf16.h>
#include <math.h>

#define NB 8
#define NIN 3136
#define NOUT 784
#define DIN 96
#define DOUT 192
#define HID 384
#define TOK_IN (NB*NIN)    // 25088
#define TOK_OUT (NB*NOUT)  // 6272

// ---------------- weight transposes (once per launch)
// wct  : [ch][kh][ci4m][kw][co][4]   (ci = ch*48 + ci4m*4 + q)
// wkv4 : [e4][288][4]   (cols 0..95 = k_w, 96..287 = v_w)
// qw4  : [e4][96][4]
// w1_4 : [e4][384][4]
// w2_4 : [h4][192][4]
__global__ void k_tr(const float* __restrict__ cw, const float* __restrict__ kw,
                     const float* __restrict__ vw, const float* __restrict__ qw,
                     const float* __restrict__ w1, const float* __restrict__ w2,
                     float* __restrict__ wct, float* __restrict__ wkv4, float* __restrict__ qw4,
                     float* __restrict__ w1_4, float* __restrict__ w2_4) {
  int i = blockIdx.x * 256 + threadIdx.x;
  if (i < 165888) {
    int q = i & 3; int t1 = i >> 2;
    int co = t1 % 192; int t2 = t1 / 192;
    int kwi = t2 % 3; int t3 = t2 / 3;
    int ci4m = t3 % 12; int t4 = t3 / 12;
    int kh = t4 % 3; int ch = t4 / 3;
    wct[i] = cw[((co*96 + ch*48 + ci4m*4 + q)*3 + kh)*3 + kwi];
  } else if (i < 165888 + 27648) {
    int j = i - 165888; int q = j & 3; int rest = j >> 2;
    int o = rest % 288; int e = (rest / 288)*4 + q;
    wkv4[j] = (o < 96) ? kw[o*96 + e] : vw[(o-96)*96 + e];
  } else if (i < 165888 + 27648 + 18432) {
    int j = i - 165888 - 27648; int q = j & 3; int rest = j >> 2;
    int o = rest % 96; int e = (rest / 96)*4 + q;
    qw4[j] = qw[o*192 + e];
  } else if (i < 165888 + 27648 + 18432 + 73728) {
    int j = i - 165888 - 27648 - 18432; int q = j & 3; int rest = j >> 2;
    int hh = rest % 384; int e = (rest / 384)*4 + q;
    w1_4[j] = w1[hh*192 + e];
  } else if (i < 165888 + 27648 + 18432 + 73728 + 73728) {
    int j = i - 165888 - 27648 - 18432 - 73728; int q = j & 3; int rest = j >> 2;
    int o = rest % 192; int h = (rest / 192)*4 + q;
    w2_4[j] = w2[o*384 + h];
  }
}

// ---------------- strided 3x3 conv seed, ci-split partial sums.
// grid (28 ho, 4 = half + 2*ch, 8 b), 224 thr = 7 groups x 32 lanes; TM=4 wo, TN=3 co.
__global__ __launch_bounds__(224) void k_conv(const float* __restrict__ x,
                                              const float* __restrict__ wct,
                                              float* __restrict__ seed0,
                                              float* __restrict__ seed1) {
  __shared__ float xs[3][58][48];   // 33.4 KB: full-row halo tile, ci-half
  int ho = blockIdx.x;
  int half = blockIdx.y & 1, ch = blockIdx.y >> 1;
  int b = blockIdx.z;
  int t = threadIdx.x;
  const float* xb0 = x + (size_t)b*NIN*DIN + ch*48;
  for (int i = t; i < 3*58*12; i += 224) {
    int q = i % 12; int rest = i / 12;
    int col = rest % 58; int kh = rest / 58;
    int h = 2*ho - 1 + kh, c = col - 1;
    float4 v = make_float4(0.f,0.f,0.f,0.f);
    if (h >= 0 && h < 56 && c >= 0 && c < 56)
      v = *(const float4*)(xb0 + ((size_t)h*56 + c)*DIN + q*4);
    *(float4*)&xs[kh][col][q*4] = v;
  }
  __syncthreads();
  int ol = t & 31, tg = t >> 5;       // tg in [0,7): wo = 4tg..4tg+3
  int co = half*96 + ol;
  float acc[4][3];
  #pragma unroll
  for (int i = 0; i < 4; i++) { acc[i][0]=0.f; acc[i][1]=0.f; acc[i][2]=0.f; }
  #pragma unroll
  for (int kh = 0; kh < 3; kh++) {
    const float4* wp = (const float4*)wct + ((size_t)((ch*3 + kh)*12)*3)*192 + co;
    const float* xb = &xs[kh][8*tg][0];
    #pragma unroll 4
    for (int ci4 = 0; ci4 < 12; ci4++) {
      float4 xr[9];
      #pragma unroll
      for (int c = 0; c < 9; c++) xr[c] = *(const float4*)(xb + c*48);
      #pragma unroll
      for (int kwv = 0; kwv < 3; kwv++) {
        float4 w0 = wp[kwv*192], w1 = wp[kwv*192 + 32], w2 = wp[kwv*192 + 64];
        #pragma unroll
        for (int i = 0; i < 4; i++) {
          float4 xv = xr[2*i + kwv];
          acc[i][0] += xv.x*w0.x + xv.y*w0.y + xv.z*w0.z + xv.w*w0.w;
          acc[i][1] += xv.x*w1.x + xv.y*w1.y + xv.z*w1.z + xv.w*w1.w;
          acc[i][2] += xv.x*w2.x + xv.y*w2.y + xv.z*w2.z + xv.w*w2.w;
        }
      }
      wp += 576; xb += 4;
    }
  }
  float* sp = (ch == 0) ? seed0 : seed1;
  #pragma unroll
  for (int i = 0; i < 4; i++)
    #pragma unroll
    for (int j = 0; j < 3; j++)
      sp[((size_t)b*NOUT + ho*28 + 4*tg + i)*DOUT + co + 32*j] = acc[i][j];
}

// ---------------- seed-sum + LN -> xo, + LN + q-GEMM -> qb. 16 tok/block, 256 thr
__global__ __launch_bounds__(256) void k_lnq(const float* __restrict__ seed0,
                                             const float* __restrict__ seed1,
                                             const float* __restrict__ qw4,
                                             const float* __restrict__ lng, const float* __restrict__ lnb,
                                             float* __restrict__ xo, float* __restrict__ qb) {
  __shared__ float xt[16][196];
  int tok0 = blockIdx.x * 16;
  int t = threadIdx.x;
  int tok16 = t >> 4, l16 = t & 15;
  size_t base = (size_t)(tok0 + tok16)*DOUT;
  float v[12], s = 0.f, sq = 0.f;
  #pragma unroll
  for (int j = 0; j < 12; j++) {
    int e = l16 + 16*j;
    float vv = seed0[base + e] + seed1[base + e];
    v[j] = vv; s += vv; sq += vv*vv;
  }
  #pragma unroll
  for (int off = 8; off; off >>= 1) { s += __shfl_xor(s, off, 16); sq += __shfl_xor(sq, off, 16); }
  float mu = s * (1.f/192.f);
  float var = sq * (1.f/192.f) - mu*mu;
  float rs = rsqrtf(var + 1e-5f);
  float s2 = 0.f, sq2 = 0.f;
  #pragma unroll
  for (int j = 0; j < 12; j++) {
    int e = l16 + 16*j;
    float y = (v[j]-mu)*rs*lng[e] + lnb[e];
    xo[base + e] = y;
    v[j] = y; s2 += y; sq2 += y*y;
  }
  #pragma unroll
  for (int off = 8; off; off >>= 1) { s2 += __shfl_xor(s2, off, 16); sq2 += __shfl_xor(sq2, off, 16); }
  float mu2 = s2 * (1.f/192.f);
  float var2 = sq2 * (1.f/192.f) - mu2*mu2;
  float rs2 = rsqrtf(var2 + 1e-5f);
  #pragma unroll
  for (int j = 0; j < 12; j++) {
    int e = l16 + 16*j;
    xt[tok16][e] = (v[j]-mu2)*rs2*lng[e] + lnb[e];
  }
  __syncthreads();
  int ol = t & 31, tg = t >> 5;
  float acc[2][3];
  #pragma unroll
  for (int i = 0; i < 2; i++) { acc[i][0]=0.f; acc[i][1]=0.f; acc[i][2]=0.f; }
  const float4* wp = (const float4*)qw4 + ol;
  for (int e4 = 0; e4 < 48; e4++) {
    float4 w0 = wp[0], w1 = wp[32], w2 = wp[64];
    #pragma unroll
    for (int i = 0; i < 2; i++) {
      float4 xv = *(const float4*)&xt[tg*2+i][e4*4];
      acc[i][0] += xv.x*w0.x + xv.y*w0.y + xv.z*w0.z + xv.w*w0.w;
      acc[i][1] += xv.x*w1.x + xv.y*w1.y + xv.z*w1.z + xv.w*w1.w;
      acc[i][2] += xv.x*w2.x + xv.y*w2.y + xv.z*w2.z + xv.w*w2.w;
    }
    wp += 96;
  }
  #pragma unroll
  for (int i = 0; i < 2; i++)
    #pragma unroll
    for (int j = 0; j < 3; j++)
      qb[(size_t)(tok0 + tg*2 + i)*DIN + ol + 32*j] = acc[i][j];
}

// ---------------- kv = LN(x) @ [k_w|v_w]^T, LN fused. 64 tokens/block, 512 thr
__global__ __launch_bounds__(512) void k_kv(const float* __restrict__ x,
                                            const float* __restrict__ wkv4,
                                            const float* __restrict__ lng, const float* __restrict__ lnb,
                                            float* __restrict__ kvb) {
  __shared__ float xt[64][100];
  int tok0 = blockIdx.x * 64;
  int t = threadIdx.x;
  const float4* xp = (const float4*)(x + (size_t)tok0*DIN);
  for (int i = t; i < 64*24; i += 512) {
    int tok = i / 24, q = i % 24;
    *(float4*)&xt[tok][q*4] = xp[i];
  }
  __syncthreads();
  int tok8 = t >> 3, l8 = t & 7;
  float vv[12], s = 0.f, sq = 0.f;
  #pragma unroll
  for (int j = 0; j < 12; j++) {
    float v = xt[tok8][l8 + 8*j];
    vv[j] = v; s += v; sq += v*v;
  }
  #pragma unroll
  for (int off = 4; off; off >>= 1) { s += __shfl_xor(s, off, 8); sq += __shfl_xor(sq, off, 8); }
  float mu = s * (1.f/96.f);
  float var = sq * (1.f/96.f) - mu*mu;
  float rs = rsqrtf(var + 1e-5f);
  #pragma unroll
  for (int j = 0; j < 12; j++) {
    int e = l8 + 8*j;
    xt[tok8][e] = (vv[j]-mu)*rs*lng[e] + lnb[e];
  }
  __syncthreads();
  int ol = t & 31, tg = t >> 5;     // 16 groups x 4 tokens
  float acc[4][9];
  #pragma unroll
  for (int i = 0; i < 4; i++)
    #pragma unroll
    for (int j = 0; j < 9; j++) acc[i][j] = 0.f;
  const float4* wp = (const float4*)wkv4 + ol;
  for (int e4 = 0; e4 < 24; e4++) {
    float4 w[9];
    #pragma unroll
    for (int j = 0; j < 9; j++) w[j] = wp[32*j];
    #pragma unroll
    for (int i = 0; i < 4; i++) {
      float4 xv = *(const float4*)&xt[tg*4+i][e4*4];
      #pragma unroll
      for (int j = 0; j < 9; j++)
        acc[i][j] += xv.x*w[j].x + xv.y*w[j].y + xv.z*w[j].z + xv.w*w[j].w;
    }
    wp += 288;
  }
  #pragma unroll
  for (int i = 0; i < 4; i++)
    #pragma unroll
    for (int j = 0; j < 9; j++)
      kvb[(size_t)(tok0 + tg*4 + i)*288 + ol + 32*j] = acc[i][j];
}

// ---------------- window helper
__device__ __forceinline__ void window9(int n, int* ms, bool* dup) {
  int r = n / 56, c = n % 56;
  int rb = r >> 1, cb = c >> 1;
  #pragma unroll
  for (int j = 0; j < 9; j++) {
    int ro = rb + (j/3) - 1; ro = ro < 0 ? 0 : (ro > 27 ? 27 : ro);
    int co = cb + (j%3) - 1; co = co < 0 ? 0 : (co > 27 ? 27 : co);
    ms[j] = ro*28 + co;
  }
  #pragma unroll
  for (int j = 0; j < 9; j++) {
    bool d = false;
    #pragma unroll
    for (int i = 0; i < j; i++) d = d || (ms[i] == ms[j]);
    dup[j] = d;
  }
}

// ---------------- sparse logits + softmax + a_ups. one wave per (b,n). no atomics.
__global__ __launch_bounds__(256) void k_attn1(const float* __restrict__ kvb,
                                               const float* __restrict__ qb,
                                               const float* __restrict__ tau,
                                               const float* __restrict__ rpb,
                                               const int* __restrict__ qidx,
                                               float* __restrict__ aups) {
  int wid = blockIdx.x * 4 + (threadIdx.x >> 6);
  int l = threadIdx.x & 63;
  int b = wid / NIN, n = wid % NIN;
  int ms[9]; bool dup[9];
  window9(n, ms, dup);
  const float* kp = kvb + (size_t)wid * 288;
  float k0 = kp[l];
  float k1 = (l < 32) ? kp[64 + l] : 0.0f;
  int l32 = 64 + (l & 31);
  float et = expf(tau[0]);
  float p[9];
  #pragma unroll
  for (int j = 0; j < 9; j++) {
    const float* qp = qb + (size_t)(b*NOUT + ms[j]) * DIN;
    p[j] = k0 * qp[l] + k1 * qp[l32];
  }
  #pragma unroll
  for (int off = 32; off; off >>= 1)
    #pragma unroll
    for (int j = 0; j < 9; j++) p[j] += __shfl_xor(p[j], off);
  float lg[9];
  #pragma unroll
  for (int j = 0; j < 9; j++)
    lg[j] = dup[j] ? -1e30f : p[j] * et + rpb[qidx[(size_t)n*NOUT + ms[j]]];
  float mx = lg[0];
  #pragma unroll
  for (int j = 1; j < 9; j++) mx = fmaxf(mx, lg[j]);
  float s = 0.f, ex[9];
  #pragma unroll
  for (int j = 0; j < 9; j++) { ex[j] = dup[j] ? 0.f : expf(lg[j] - mx); s += ex[j]; }
  float inv = 1.0f / s;
  #pragma unroll
  for (int j = 0; j < 9; j++) {
    if (l == j && !dup[j])
      aups[(size_t)wid*NOUT + ms[j]] = ex[j] * inv;
  }
}

// ---------------- updates gather + LOCAL colsum + LN + residual (+ a_down last iter)
__global__ __launch_bounds__(192) void k_upd(const float* __restrict__ aups,
                                             const float* __restrict__ kvb,
                                             float* __restrict__ xout,
                                             const float* __restrict__ g,
                                             const float* __restrict__ bb,
                                             float* __restrict__ adown, int wadown) {
  __shared__ float avals[4][64];
  __shared__ float red[4][3][2];
  __shared__ float bc[4][2];
  __shared__ float csv[4];
  int b = blockIdx.z;
  int ro0 = blockIdx.y*2, co0 = blockIdx.x*2;
  int r0 = 2*ro0 - 2; if (r0 < 0) r0 = 0;
  int r1 = 2*ro0 + 5; if (r1 > 55) r1 = 55;
  int c0 = 2*co0 - 2; if (c0 < 0) c0 = 0;
  int c1 = 2*co0 + 5; if (c1 > 55) c1 = 55;
  int nr = r1 - r0 + 1, nc = c1 - c0 + 1, cnt = nr*nc;
  int t = threadIdx.x;
  int m0 = ro0*28 + co0, m1 = m0+1, m2 = m0+28, m3 = m0+29;
  if (t < cnt) {
    int ri = t / nc, ci = t % nc;
    int n = (r0 + ri)*56 + (c0 + ci);
    const float* ap = aups + ((size_t)b*NIN + n)*NOUT;
    avals[0][t] = ap[m0]; avals[1][t] = ap[m1];
    avals[2][t] = ap[m2]; avals[3][t] = ap[m3];
  } else if (t < 64) {
    avals[0][t] = 0.f; avals[1][t] = 0.f; avals[2][t] = 0.f; avals[3][t] = 0.f;
  }
  __syncthreads();
  if (t < 64) {    // colsum over the contributor rect (covers all contributors; rest are 0)
    float cv0 = avals[0][t], cv1 = avals[1][t], cv2 = avals[2][t], cv3 = avals[3][t];
    #pragma unroll
    for (int off = 32; off; off >>= 1) {
      cv0 += __shfl_xor(cv0, off); cv1 += __shfl_xor(cv1, off);
      cv2 += __shfl_xor(cv2, off); cv3 += __shfl_xor(cv3, off);
    }
    if (t == 0) { csv[0]=cv0; csv[1]=cv1; csv[2]=cv2; csv[3]=cv3; }
  }
  __syncthreads();
  float a0=0.f, a1=0.f, a2=0.f, a3=0.f;
  int i = 0;
  for (int ri = 0; ri < nr; ri++) {
    int nbase = (r0 + ri)*56 + c0;
    for (int ci = 0; ci < nc; ci++, i++) {
      float vv = kvb[((size_t)b*NIN + nbase + ci)*288 + 96 + t];
      a0 += avals[0][i]*vv; a1 += avals[1][i]*vv;
      a2 += avals[2][i]*vv; a3 += avals[3][i]*vv;
    }
  }
  float inv0 = 1.0f/(csv[0]+1e-8f);
  float inv1 = 1.0f/(csv[1]+1e-8f);
  float inv2 = 1.0f/(csv[2]+1e-8f);
  float inv3 = 1.0f/(csv[3]+1e-8f);
  if (wadown && t < cnt) {
    int ri = t / nc, ci = t % nc;
    int n = (r0 + ri)*56 + (c0 + ci);
    float* dp = adown + ((size_t)b*NIN + n)*NOUT;
    dp[m0] = avals[0][t]*inv0; dp[m1] = avals[1][t]*inv1;
    dp[m2] = avals[2][t]*inv2; dp[m3] = avals[3][t]*inv3;
  }
  a0 *= inv0; a1 *= inv1; a2 *= inv2; a3 *= inv3;
  float s0=a0,s1=a1,s2=a2,s3=a3, q0=a0*a0,q1=a1*a1,q2=a2*a2,q3=a3*a3;
  #pragma unroll
  for (int off = 32; off; off >>= 1) {
    s0 += __shfl_xor(s0, off); q0 += __shfl_xor(q0, off);
    s1 += __shfl_xor(s1, off); q1 += __shfl_xor(q1, off);
    s2 += __shfl_xor(s2, off); q2 += __shfl_xor(q2, off);
    s3 += __shfl_xor(s3, off); q3 += __shfl_xor(q3, off);
  }
  int w = t >> 6, l = t & 63;
  if (l == 0) {
    red[0][w][0]=s0; red[0][w][1]=q0;
    red[1][w][0]=s1; red[1][w][1]=q1;
    red[2][w][0]=s2; red[2][w][1]=q2;
    red[3][w][0]=s3; red[3][w][1]=q3;
  }
  __syncthreads();
  if (t < 4) {
    float S = red[t][0][0]+red[t][1][0]+red[t][2][0];
    float Q = red[t][0][1]+red[t][1][1]+red[t][2][1];
    float mu = S * (1.0f/192.0f);
    float var = Q * (1.0f/192.0f) - mu*mu;
    bc[t][0] = mu; bc[t][1] = rsqrtf(var + 1e-5f);
  }
  __syncthreads();
  float gt = g[t], bt = bb[t];
  xout[((size_t)b*NOUT+m0)*DOUT + t] += (a0-bc[0][0])*bc[0][1]*gt + bt;
  xout[((size_t)b*NOUT+m1)*DOUT + t] += (a1-bc[1][0])*bc[1][1]*gt + bt;
  xout[((size_t)b*NOUT+m2)*DOUT + t] += (a2-bc[2][0])*bc[2][1]*gt + bt;
  xout[((size_t)b*NOUT+m3)*DOUT + t] += (a3-bc[3][0])*bc[3][1]*gt + bt;
}

// ---------------- MLP GEMM1 + GELU -> ht. 64 tokens x 96 hidden per block, TM=8 TN=3
__global__ __launch_bounds__(256) void k_mlp1(const float* __restrict__ xout,
                                              const float* __restrict__ w1_4, const float* __restrict__ b1,
                                              float* __restrict__ ht) {
  __shared__ float xt[64][196];
  int tok0 = blockIdx.x * 64;
  int h0 = blockIdx.y * 96;
  int t = threadIdx.x;
  const float4* xp = (const float4*)(xout + (size_t)tok0*DOUT);
  for (int i = t; i < 64*48; i += 256) {
    int tok = i / 48, q = i % 48;
    *(float4*)&xt[tok][q*4] = xp[i];
  }
  __syncthreads();
  int ol = t & 31, tg = t >> 5;   // 8 groups x 8 tokens
  float acc[8][3];
  #pragma unroll
  for (int i = 0; i < 8; i++) { acc[i][0]=0.f; acc[i][1]=0.f; acc[i][2]=0.f; }
  const float4* wp = (const float4*)w1_4 + h0 + ol;
  for (int e4 = 0; e4 < 48; e4++) {
    float4 w0 = wp[0], w1v = wp[32], w2v = wp[64];
    #pragma unroll
    for (int i = 0; i < 8; i++) {
      float4 xv = *(const float4*)&xt[tg*8+i][e4*4];
      acc[i][0] += xv.x*w0.x + xv.y*w0.y + xv.z*w0.z + xv.w*w0.w;
      acc[i][1] += xv.x*w1v.x + xv.y*w1v.y + xv.z*w1v.z + xv.w*w1v.w;
      acc[i][2] += xv.x*w2v.x + xv.y*w2v.y + xv.z*w2v.z + xv.w*w2v.w;
    }
    wp += 384;
  }
  #pragma unroll
  for (int j = 0; j < 3; j++) {
    int hh = h0 + ol + 32*j;
    float bv = b1[hh];
    #pragma unroll
    for (int i = 0; i < 8; i++) {
      float v = acc[i][j] + bv;
      v = 0.5f*v*(1.0f + erff(v*0.70710678118f));
      ht[(size_t)(tok0 + tg*8 + i)*HID + hh] = v;
    }
  }
}

// ---------------- MLP GEMM2 + LN + residual (+dout) + LN + next-iter q. 16 tok/block
__global__ __launch_bounds__(256) void k_mlpq(float* __restrict__ xout,
                                              const float* __restrict__ ht,
                                              const float* __restrict__ w2_4, const float* __restrict__ b2,
                                              const float* __restrict__ g, const float* __restrict__ bb,
                                              const float* __restrict__ qw4,
                                              const float* __restrict__ lng, const float* __restrict__ lnb,
                                              float* __restrict__ qb,
                                              float* __restrict__ dout, int last) {
  __shared__ float hs[16][388];
  __shared__ float xt[16][196];
  int tok0 = blockIdx.x * 16;
  int t = threadIdx.x;
  const float4* hp = (const float4*)(ht + (size_t)tok0*HID);
  for (int i = t; i < 16*96; i += 256) {
    int tok = i / 96, q = i % 96;
    *(float4*)&hs[tok][q*4] = hp[i];
  }
  __syncthreads();
  int ol = t & 31, tg = t >> 5;   // 8 groups x 2 tokens
  float acc[2][6];
  #pragma unroll
  for (int i = 0; i < 2; i++)
    #pragma unroll
    for (int j = 0; j < 6; j++) acc[i][j] = 0.f;
  const float4* wp = (const float4*)w2_4 + ol;
  for (int h4 = 0; h4 < 96; h4++) {
    float4 w[6];
    #pragma unroll
    for (int j = 0; j < 6; j++) w[j] = wp[32*j];
    #pragma unroll
    for (int i = 0; i < 2; i++) {
      float4 hv = *(const float4*)&hs[tg*2+i][h4*4];
      #pragma unroll
      for (int j = 0; j < 6; j++)
        acc[i][j] += hv.x*w[j].x + hv.y*w[j].y + hv.z*w[j].z + hv.w*w[j].w;
    }
    wp += 192;
  }
  #pragma unroll
  for (int i = 0; i < 2; i++) {
    int tl = tg*2 + i;
    int tok = tok0 + tl;
    float v[6], s = 0.f, sq = 0.f;
    #pragma unroll
    for (int j = 0; j < 6; j++) {
      v[j] = acc[i][j] + b2[ol + 32*j];
      s += v[j]; sq += v[j]*v[j];
    }
    #pragma unroll
    for (int off = 16; off; off >>= 1) { s += __shfl_xor(s, off, 32); sq += __shfl_xor(sq, off, 32); }
    float mu = s * (1.f/192.f);
    float var = sq * (1.f/192.f) - mu*mu;
    float rs = rsqrtf(var + 1e-5f);
    #pragma unroll
    for (int j = 0; j < 6; j++) {
      int o = ol + 32*j;
      float nv = (v[j] - mu)*rs*g[o] + bb[o];
      size_t gi = (size_t)tok*DOUT + o;
      float nx = xout[gi] + nv;
      xout[gi] = nx;
      if (last) dout[gi] = nx;
      xt[tl][o] = nx;
    }
  }
  if (last) return;
  __syncthreads();
  // LN (ln_out) on xt, 16-lane subgroups
  {
    int tok16 = t >> 4, l16 = t & 15;
    float vv[12], s = 0.f, sq = 0.f;
    #pragma unroll
    for (int j = 0; j < 12; j++) {
      float v = xt[tok16][l16 + 16*j];
      vv[j] = v; s += v; sq += v*v;
    }
    #pragma unroll
    for (int off = 8; off; off >>= 1) { s += __shfl_xor(s, off, 16); sq += __shfl_xor(sq, off, 16); }
    float mu = s * (1.f/192.f);
    float var = sq * (1.f/192.f) - mu*mu;
    float rs = rsqrtf(var + 1e-5f);
    __syncthreads();
    #pragma unroll
    for (int j = 0; j < 12; j++) {
      int e = l16 + 16*j;
      xt[tok16][e] = (vv[j]-mu)*rs*lng[e] + lnb[e];
    }
  }
  __syncthreads();
  // q-GEMM
  float qa[2][3];
  #pragma unroll
  for (int i = 0; i < 2; i++) { qa[i][0]=0.f; qa[i][1]=0.f; qa[i][2]=0.f; }
  const float4* qp = (const float4*)qw4 + ol;
  for (int e4 = 0; e4 < 48; e4++) {
    float4 w0 = qp[0], w1 = qp[32], w2 = qp[64];
    #pragma unroll
    for (int i = 0; i < 2; i++) {
      float4 xv = *(const float4*)&xt[tg*2+i][e4*4];
      qa[i][0] += xv.x*w0.x + xv.y*w0.y + xv.z*w0.z + xv.w*w0.w;
      qa[i][1] += xv.x*w1.x + xv.y*w1.y + xv.z*w1.z + xv.w*w1.w;
      qa[i][2] += xv.x*w2.x + xv.y*w2.y + xv.z*w2.z + xv.w*w2.w;
    }
    qp += 96;
  }
  #pragma unroll
  for (int i = 0; i < 2; i++)
    #pragma unroll
    for (int j = 0; j < 3; j++)
      qb[(size_t)(tok0 + tg*2 + i)*DIN + ol + 32*j] = qa[i][j];
}

extern "C" void kernel_launch(void* const* d_in, const int* in_sizes, int n_in,
                              void* d_out, int out_size, void* d_ws, size_t ws_size,
                              hipStream_t stream) {
  (void)in_sizes; (void)n_in; (void)ws_size;
  const float* x        = (const float*)d_in[0];
  const float* conv_w   = (const float*)d_in[1];
  const float* q_w      = (const float*)d_in[2];
  const float* k_w      = (const float*)d_in[3];
  const float* v_w      = (const float*)d_in[4];
  const float* mlp_w1   = (const float*)d_in[5];
  const float* mlp_b1   = (const float*)d_in[6];
  const float* mlp_w2   = (const float*)d_in[7];
  const float* mlp_b2   = (const float*)d_in[8];
  const float* ln_in_g  = (const float*)d_in[9];
  const float* ln_in_b  = (const float*)d_in[10];
  const float* ln_out_g = (const float*)d_in[11];
  const float* ln_out_b = (const float*)d_in[12];
  const float* ln_attn_g= (const float*)d_in[13];
  const float* ln_attn_b= (const float*)d_in[14];
  const float* ln_mlp_g = (const float*)d_in[15];
  const float* ln_mlp_b = (const float*)d_in[16];
  const float* tau      = (const float*)d_in[17];
  const float* rpb      = (const float*)d_in[18];
  const int*   qidx     = (const int*)d_in[20];

  float* out = (float*)d_out;
  float* aups  = out + 1204224;       // 8*784*192
  float* adown = out + 20873216;      // + 8*3136*784

  float* ws   = (float*)d_ws;
  float* wct  = ws;                   // 165888
  float* wkv4 = wct + 165888;         // 27648
  float* qw4  = wkv4 + 27648;         // 18432
  float* w1_4 = qw4 + 18432;          // 73728
  float* w2_4 = w1_4 + 73728;         // 73728
  float* kvb  = w2_4 + 73728;         // 25088*288
  float* seed0= kvb + (size_t)TOK_IN*288;     // 6272*192
  float* seed1= seed0 + (size_t)TOK_OUT*DOUT; // 6272*192
  float* xo   = seed1 + (size_t)TOK_OUT*DOUT; // 6272*192
  float* qb   = xo + (size_t)TOK_OUT*DOUT;    // 6272*96
  float* htb  = qb + (size_t)TOK_OUT*DIN;     // 6272*384

  // zero only the sparse attention outputs; x_out region is fully overwritten
  hipMemsetAsync(aups, 0, (size_t)(out_size - 1204224) * sizeof(float), stream);

  k_tr<<<1404, 256, 0, stream>>>(conv_w, k_w, v_w, q_w, mlp_w1, mlp_w2,
                                 wct, wkv4, qw4, w1_4, w2_4);
  k_conv<<<dim3(28, 4, 8), 224, 0, stream>>>(x, wct, seed0, seed1);
  k_lnq<<<TOK_OUT/16, 256, 0, stream>>>(seed0, seed1, qw4, ln_out_g, ln_out_b, xo, qb);
  k_kv<<<TOK_IN/64, 512, 0, stream>>>(x, wkv4, ln_in_g, ln_in_b, kvb);

  for (int it = 0; it < 3; it++) {
    k_attn1<<<TOK_IN/4, 256, 0, stream>>>(kvb, qb, tau, rpb, qidx, aups);
    k_upd<<<dim3(14, 14, NB), 192, 0, stream>>>(aups, kvb, xo, ln_attn_g, ln_attn_b,
                                                adown, it == 2);
    k_mlp1<<<dim3(TOK_OUT/64, 4), 256, 0, stream>>>(xo, w1_4, mlp_b1, htb);
    k_mlpq<<<TOK_OUT/16, 256, 0, stream>>>(xo, htb, w2_4, mlp_b2,
                                           ln_mlp_g, ln_mlp_b,
                                           qw4, ln_out_g, ln_out_b, qb,
                                           out, it == 2);
  }
}

// Round 9
// 836.235 us; speedup vs baseline: 1.2867x; 1.0204x over previous
//
#include <hip/hip_runtime.h>
#include <hip/hip_bf16.h>
#include <math.h>

#define NB 8
#define NIN 3136
#define NOUT 784
#define DIN 96
#define DOUT 192
#define HID 384
#define TOK_IN (NB*NIN)    // 25088
#define TOK_OUT (NB*NOUT)  // 6272

// ---------------- window helper
__device__ __forceinline__ void window9(int n, int* ms, bool* dup) {
  int r = n / 56, c = n % 56;
  int rb = r >> 1, cb = c >> 1;
  #pragma unroll
  for (int j = 0; j < 9; j++) {
    int ro = rb + (j/3) - 1; ro = ro < 0 ? 0 : (ro > 27 ? 27 : ro);
    int co = cb + (j%3) - 1; co = co < 0 ? 0 : (co > 27 ? 27 : co);
    ms[j] = ro*28 + co;
  }
  #pragma unroll
  for (int j = 0; j < 9; j++) {
    bool d = false;
    #pragma unroll
    for (int i = 0; i < j; i++) d = d || (ms[i] == ms[j]);
    dup[j] = d;
  }
}

// ---------------- weight transposes + bias9 table (once per launch)
// wct  : [ch][kh][ci4m][kw][co][4]   (ci = ch*48 + ci4m*4 + q)
// wkv4 : [e4][288][4]   (cols 0..95 = k_w, 96..287 = v_w)
// qw4  : [e4][96][4]
// w1_4 : [e4][384][4]
// w2_4 : [h4][192][4]
// bias9: [n][9] = rpb[qidx[n, ms_j(n)]]
__global__ void k_tr(const float* __restrict__ cw, const float* __restrict__ kw,
                     const float* __restrict__ vw, const float* __restrict__ qw,
                     const float* __restrict__ w1, const float* __restrict__ w2,
                     const float* __restrict__ rpb, const int* __restrict__ qidx,
                     float* __restrict__ wct, float* __restrict__ wkv4, float* __restrict__ qw4,
                     float* __restrict__ w1_4, float* __restrict__ w2_4,
                     float* __restrict__ bias9) {
  int i = blockIdx.x * 256 + threadIdx.x;
  if (i < 165888) {
    int q = i & 3; int t1 = i >> 2;
    int co = t1 % 192; int t2 = t1 / 192;
    int kwi = t2 % 3; int t3 = t2 / 3;
    int ci4m = t3 % 12; int t4 = t3 / 12;
    int kh = t4 % 3; int ch = t4 / 3;
    wct[i] = cw[((co*96 + ch*48 + ci4m*4 + q)*3 + kh)*3 + kwi];
  } else if (i < 165888 + 27648) {
    int j = i - 165888; int q = j & 3; int rest = j >> 2;
    int o = rest % 288; int e = (rest / 288)*4 + q;
    wkv4[j] = (o < 96) ? kw[o*96 + e] : vw[(o-96)*96 + e];
  } else if (i < 165888 + 27648 + 18432) {
    int j = i - 165888 - 27648; int q = j & 3; int rest = j >> 2;
    int o = rest % 96; int e = (rest / 96)*4 + q;
    qw4[j] = qw[o*192 + e];
  } else if (i < 165888 + 27648 + 18432 + 73728) {
    int j = i - 165888 - 27648 - 18432; int q = j & 3; int rest = j >> 2;
    int hh = rest % 384; int e = (rest / 384)*4 + q;
    w1_4[j] = w1[hh*192 + e];
  } else if (i < 165888 + 27648 + 18432 + 73728 + 73728) {
    int j = i - 165888 - 27648 - 18432 - 73728; int q = j & 3; int rest = j >> 2;
    int o = rest % 192; int h = (rest / 192)*4 + q;
    w2_4[j] = w2[o*384 + h];
  } else if (i < 165888 + 27648 + 18432 + 73728 + 73728 + 28224) {
    int j = i - 165888 - 27648 - 18432 - 73728 - 73728;
    int j9 = j % 9; int n = j / 9;
    int ms[9]; bool dup[9];
    window9(n, ms, dup);
    bias9[j] = rpb[qidx[(size_t)n*NOUT + ms[j9]]];
  }
}

// ---------------- strided 3x3 conv seed, ci-split partial sums.
// grid (28 ho, 4 = half + 2*ch, 8 b), 224 thr = 7 groups x 32 lanes; TM=4 wo, TN=3 co.
__global__ __launch_bounds__(224, 4) void k_conv(const float* __restrict__ x,
                                                 const float* __restrict__ wct,
                                                 float* __restrict__ seed0,
                                                 float* __restrict__ seed1) {
  __shared__ float xs[3][58][48];   // 33.4 KB: full-row halo tile, ci-half
  int ho = blockIdx.x;
  int half = blockIdx.y & 1, ch = blockIdx.y >> 1;
  int b = blockIdx.z;
  int t = threadIdx.x;
  const float* xb0 = x + (size_t)b*NIN*DIN + ch*48;
  for (int i = t; i < 3*58*12; i += 224) {
    int q = i % 12; int rest = i / 12;
    int col = rest % 58; int kh = rest / 58;
    int h = 2*ho - 1 + kh, c = col - 1;
    float4 v = make_float4(0.f,0.f,0.f,0.f);
    if (h >= 0 && h < 56 && c >= 0 && c < 56)
      v = *(const float4*)(xb0 + ((size_t)h*56 + c)*DIN + q*4);
    *(float4*)&xs[kh][col][q*4] = v;
  }
  __syncthreads();
  int ol = t & 31, tg = t >> 5;       // tg in [0,7): wo = 4tg..4tg+3
  int co = half*96 + ol;
  float acc[4][3];
  #pragma unroll
  for (int i = 0; i < 4; i++) { acc[i][0]=0.f; acc[i][1]=0.f; acc[i][2]=0.f; }
  #pragma unroll
  for (int kh = 0; kh < 3; kh++) {
    const float4* wp = (const float4*)wct + ((size_t)((ch*3 + kh)*12)*3)*192 + co;
    const float* xb = &xs[kh][8*tg][0];
    #pragma unroll 4
    for (int ci4 = 0; ci4 < 12; ci4++) {
      float4 xr[9];
      #pragma unroll
      for (int c = 0; c < 9; c++) xr[c] = *(const float4*)(xb + c*48);
      #pragma unroll
      for (int kwv = 0; kwv < 3; kwv++) {
        float4 w0 = wp[kwv*192], w1 = wp[kwv*192 + 32], w2 = wp[kwv*192 + 64];
        #pragma unroll
        for (int i = 0; i < 4; i++) {
          float4 xv = xr[2*i + kwv];
          acc[i][0] += xv.x*w0.x + xv.y*w0.y + xv.z*w0.z + xv.w*w0.w;
          acc[i][1] += xv.x*w1.x + xv.y*w1.y + xv.z*w1.z + xv.w*w1.w;
          acc[i][2] += xv.x*w2.x + xv.y*w2.y + xv.z*w2.z + xv.w*w2.w;
        }
      }
      wp += 576; xb += 4;
    }
  }
  float* sp = (ch == 0) ? seed0 : seed1;
  #pragma unroll
  for (int i = 0; i < 4; i++)
    #pragma unroll
    for (int j = 0; j < 3; j++)
      sp[((size_t)b*NOUT + ho*28 + 4*tg + i)*DOUT + co + 32*j] = acc[i][j];
}

// ---------------- seed-sum + LN -> xo, + LN + q-GEMM -> qb. 16 tok/block, 256 thr
__global__ __launch_bounds__(256) void k_lnq(const float* __restrict__ seed0,
                                             const float* __restrict__ seed1,
                                             const float* __restrict__ qw4,
                                             const float* __restrict__ lng, const float* __restrict__ lnb,
                                             float* __restrict__ xo, float* __restrict__ qb) {
  __shared__ float xt[16][196];
  int tok0 = blockIdx.x * 16;
  int t = threadIdx.x;
  int tok16 = t >> 4, l16 = t & 15;
  size_t base = (size_t)(tok0 + tok16)*DOUT;
  float v[12], s = 0.f, sq = 0.f;
  #pragma unroll
  for (int j = 0; j < 12; j++) {
    int e = l16 + 16*j;
    float vv = seed0[base + e] + seed1[base + e];
    v[j] = vv; s += vv; sq += vv*vv;
  }
  #pragma unroll
  for (int off = 8; off; off >>= 1) { s += __shfl_xor(s, off, 16); sq += __shfl_xor(sq, off, 16); }
  float mu = s * (1.f/192.f);
  float var = sq * (1.f/192.f) - mu*mu;
  float rs = rsqrtf(var + 1e-5f);
  float s2 = 0.f, sq2 = 0.f;
  #pragma unroll
  for (int j = 0; j < 12; j++) {
    int e = l16 + 16*j;
    float y = (v[j]-mu)*rs*lng[e] + lnb[e];
    xo[base + e] = y;
    v[j] = y; s2 += y; sq2 += y*y;
  }
  #pragma unroll
  for (int off = 8; off; off >>= 1) { s2 += __shfl_xor(s2, off, 16); sq2 += __shfl_xor(sq2, off, 16); }
  float mu2 = s2 * (1.f/192.f);
  float var2 = sq2 * (1.f/192.f) - mu2*mu2;
  float rs2 = rsqrtf(var2 + 1e-5f);
  #pragma unroll
  for (int j = 0; j < 12; j++) {
    int e = l16 + 16*j;
    xt[tok16][e] = (v[j]-mu2)*rs2*lng[e] + lnb[e];
  }
  __syncthreads();
  int ol = t & 31, tg = t >> 5;
  float acc[2][3];
  #pragma unroll
  for (int i = 0; i < 2; i++) { acc[i][0]=0.f; acc[i][1]=0.f; acc[i][2]=0.f; }
  const float4* wp = (const float4*)qw4 + ol;
  for (int e4 = 0; e4 < 48; e4++) {
    float4 w0 = wp[0], w1 = wp[32], w2 = wp[64];
    #pragma unroll
    for (int i = 0; i < 2; i++) {
      float4 xv = *(const float4*)&xt[tg*2+i][e4*4];
      acc[i][0] += xv.x*w0.x + xv.y*w0.y + xv.z*w0.z + xv.w*w0.w;
      acc[i][1] += xv.x*w1.x + xv.y*w1.y + xv.z*w1.z + xv.w*w1.w;
      acc[i][2] += xv.x*w2.x + xv.y*w2.y + xv.z*w2.z + xv.w*w2.w;
    }
    wp += 96;
  }
  #pragma unroll
  for (int i = 0; i < 2; i++)
    #pragma unroll
    for (int j = 0; j < 3; j++)
      qb[(size_t)(tok0 + tg*2 + i)*DIN + ol + 32*j] = acc[i][j];
}

// ---------------- kv = LN(x) @ [k_w|v_w]^T, LN fused. 64 tokens/block, 512 thr
__global__ __launch_bounds__(512) void k_kv(const float* __restrict__ x,
                                            const float* __restrict__ wkv4,
                                            const float* __restrict__ lng, const float* __restrict__ lnb,
                                            float* __restrict__ kvb) {
  __shared__ float xt[64][100];
  int tok0 = blockIdx.x * 64;
  int t = threadIdx.x;
  const float4* xp = (const float4*)(x + (size_t)tok0*DIN);
  for (int i = t; i < 64*24; i += 512) {
    int tok = i / 24, q = i % 24;
    *(float4*)&xt[tok][q*4] = xp[i];
  }
  __syncthreads();
  int tok8 = t >> 3, l8 = t & 7;
  float vv[12], s = 0.f, sq = 0.f;
  #pragma unroll
  for (int j = 0; j < 12; j++) {
    float v = xt[tok8][l8 + 8*j];
    vv[j] = v; s += v; sq += v*v;
  }
  #pragma unroll
  for (int off = 4; off; off >>= 1) { s += __shfl_xor(s, off, 8); sq += __shfl_xor(sq, off, 8); }
  float mu = s * (1.f/96.f);
  float var = sq * (1.f/96.f) - mu*mu;
  float rs = rsqrtf(var + 1e-5f);
  #pragma unroll
  for (int j = 0; j < 12; j++) {
    int e = l8 + 8*j;
    xt[tok8][e] = (vv[j]-mu)*rs*lng[e] + lnb[e];
  }
  __syncthreads();
  int ol = t & 31, tg = t >> 5;     // 16 groups x 4 tokens
  float acc[4][9];
  #pragma unroll
  for (int i = 0; i < 4; i++)
    #pragma unroll
    for (int j = 0; j < 9; j++) acc[i][j] = 0.f;
  const float4* wp = (const float4*)wkv4 + ol;
  for (int e4 = 0; e4 < 24; e4++) {
    float4 w[9];
    #pragma unroll
    for (int j = 0; j < 9; j++) w[j] = wp[32*j];
    #pragma unroll
    for (int i = 0; i < 4; i++) {
      float4 xv = *(const float4*)&xt[tg*4+i][e4*4];
      #pragma unroll
      for (int j = 0; j < 9; j++)
        acc[i][j] += xv.x*w[j].x + xv.y*w[j].y + xv.z*w[j].z + xv.w*w[j].w;
    }
    wp += 288;
  }
  #pragma unroll
  for (int i = 0; i < 4; i++)
    #pragma unroll
    for (int j = 0; j < 9; j++)
      kvb[(size_t)(tok0 + tg*4 + i)*288 + ol + 32*j] = acc[i][j];
}

// ---------------- sparse logits + softmax + a_ups. one wave per (b,n).
// zmode: also write full zero rows (aups with embedded values, adown zeros).
__global__ __launch_bounds__(256) void k_attn1(const float* __restrict__ kvb,
                                               const float* __restrict__ qb,
                                               const float* __restrict__ tau,
                                               const float* __restrict__ bias9,
                                               float* __restrict__ aups,
                                               float* __restrict__ adown, int zmode) {
  int wid = blockIdx.x * 4 + (threadIdx.x >> 6);
  int l = threadIdx.x & 63;
  int b = wid / NIN, n = wid % NIN;
  int ms[9]; bool dup[9];
  window9(n, ms, dup);
  const float* kp = kvb + (size_t)wid * 288;
  float k0 = kp[l];
  float k1 = (l < 32) ? kp[64 + l] : 0.0f;
  int l32 = 64 + (l & 31);
  float et = expf(tau[0]);
  float p[9];
  #pragma unroll
  for (int j = 0; j < 9; j++) {
    const float* qp = qb + (size_t)(b*NOUT + ms[j]) * DIN;
    p[j] = k0 * qp[l] + k1 * qp[l32];
  }
  #pragma unroll
  for (int off = 32; off; off >>= 1)
    #pragma unroll
    for (int j = 0; j < 9; j++) p[j] += __shfl_xor(p[j], off);
  const float* bp = bias9 + (size_t)n*9;
  float lg[9];
  #pragma unroll
  for (int j = 0; j < 9; j++)
    lg[j] = dup[j] ? -1e30f : p[j] * et + bp[j];
  float mx = lg[0];
  #pragma unroll
  for (int j = 1; j < 9; j++) mx = fmaxf(mx, lg[j]);
  float s = 0.f, ex[9];
  #pragma unroll
  for (int j = 0; j < 9; j++) { ex[j] = dup[j] ? 0.f : expf(lg[j] - mx); s += ex[j]; }
  float inv = 1.0f / s;
  if (zmode) {
    // full-row write: zeros + embedded values (all lanes know all a_j)
    float* ap = aups + (size_t)wid*NOUT;
    float* dp = adown + (size_t)wid*NOUT;
    #pragma unroll
    for (int k = 0; k < 13; k++) {
      int e = l + 64*k;
      if (e < NOUT) {
        float v = 0.f;
        #pragma unroll
        for (int j = 0; j < 9; j++)
          if (!dup[j] && e == ms[j]) v = ex[j] * inv;
        ap[e] = v;
        dp[e] = 0.f;
      }
    }
  } else {
    #pragma unroll
    for (int j = 0; j < 9; j++) {
      if (l == j && !dup[j])
        aups[(size_t)wid*NOUT + ms[j]] = ex[j] * inv;
    }
  }
}

// ---------------- updates gather + LOCAL colsum + LN + residual (+ a_down last iter)
__global__ __launch_bounds__(192) void k_upd(const float* __restrict__ aups,
                                             const float* __restrict__ kvb,
                                             float* __restrict__ xout,
                                             const float* __restrict__ g,
                                             const float* __restrict__ bb,
                                             float* __restrict__ adown, int wadown) {
  __shared__ float avals[4][64];
  __shared__ float red[4][3][2];
  __shared__ float bc[4][2];
  __shared__ float csv[4];
  int b = blockIdx.z;
  int ro0 = blockIdx.y*2, co0 = blockIdx.x*2;
  int r0 = 2*ro0 - 2; if (r0 < 0) r0 = 0;
  int r1 = 2*ro0 + 5; if (r1 > 55) r1 = 55;
  int c0 = 2*co0 - 2; if (c0 < 0) c0 = 0;
  int c1 = 2*co0 + 5; if (c1 > 55) c1 = 55;
  int nr = r1 - r0 + 1, nc = c1 - c0 + 1, cnt = nr*nc;
  int t = threadIdx.x;
  int m0 = ro0*28 + co0, m1 = m0+1, m2 = m0+28, m3 = m0+29;
  if (t < cnt) {
    int ri = t / nc, ci = t % nc;
    int n = (r0 + ri)*56 + (c0 + ci);
    const float* ap = aups + ((size_t)b*NIN + n)*NOUT;
    avals[0][t] = ap[m0]; avals[1][t] = ap[m1];
    avals[2][t] = ap[m2]; avals[3][t] = ap[m3];
  } else if (t < 64) {
    avals[0][t] = 0.f; avals[1][t] = 0.f; avals[2][t] = 0.f; avals[3][t] = 0.f;
  }
  __syncthreads();
  if (t < 64) {    // colsum over the contributor rect (covers all contributors; rest are 0)
    float cv0 = avals[0][t], cv1 = avals[1][t], cv2 = avals[2][t], cv3 = avals[3][t];
    #pragma unroll
    for (int off = 32; off; off >>= 1) {
      cv0 += __shfl_xor(cv0, off); cv1 += __shfl_xor(cv1, off);
      cv2 += __shfl_xor(cv2, off); cv3 += __shfl_xor(cv3, off);
    }
    if (t == 0) { csv[0]=cv0; csv[1]=cv1; csv[2]=cv2; csv[3]=cv3; }
  }
  __syncthreads();
  float a0=0.f, a1=0.f, a2=0.f, a3=0.f;
  int i = 0;
  for (int ri = 0; ri < nr; ri++) {
    int nbase = (r0 + ri)*56 + c0;
    for (int ci = 0; ci < nc; ci++, i++) {
      float vv = kvb[((size_t)b*NIN + nbase + ci)*288 + 96 + t];
      a0 += avals[0][i]*vv; a1 += avals[1][i]*vv;
      a2 += avals[2][i]*vv; a3 += avals[3][i]*vv;
    }
  }
  float inv0 = 1.0f/(csv[0]+1e-8f);
  float inv1 = 1.0f/(csv[1]+1e-8f);
  float inv2 = 1.0f/(csv[2]+1e-8f);
  float inv3 = 1.0f/(csv[3]+1e-8f);
  if (wadown && t < cnt) {
    int ri = t / nc, ci = t % nc;
    int n = (r0 + ri)*56 + (c0 + ci);
    float* dp = adown + ((size_t)b*NIN + n)*NOUT;
    dp[m0] = avals[0][t]*inv0; dp[m1] = avals[1][t]*inv1;
    dp[m2] = avals[2][t]*inv2; dp[m3] = avals[3][t]*inv3;
  }
  a0 *= inv0; a1 *= inv1; a2 *= inv2; a3 *= inv3;
  float s0=a0,s1=a1,s2=a2,s3=a3, q0=a0*a0,q1=a1*a1,q2=a2*a2,q3=a3*a3;
  #pragma unroll
  for (int off = 32; off; off >>= 1) {
    s0 += __shfl_xor(s0, off); q0 += __shfl_xor(q0, off);
    s1 += __shfl_xor(s1, off); q1 += __shfl_xor(q1, off);
    s2 += __shfl_xor(s2, off); q2 += __shfl_xor(q2, off);
    s3 += __shfl_xor(s3, off); q3 += __shfl_xor(q3, off);
  }
  int w = t >> 6, l = t & 63;
  if (l == 0) {
    red[0][w][0]=s0; red[0][w][1]=q0;
    red[1][w][0]=s1; red[1][w][1]=q1;
    red[2][w][0]=s2; red[2][w][1]=q2;
    red[3][w][0]=s3; red[3][w][1]=q3;
  }
  __syncthreads();
  if (t < 4) {
    float S = red[t][0][0]+red[t][1][0]+red[t][2][0];
    float Q = red[t][0][1]+red[t][1][1]+red[t][2][1];
    float mu = S * (1.0f/192.0f);
    float var = Q * (1.0f/192.0f) - mu*mu;
    bc[t][0] = mu; bc[t][1] = rsqrtf(var + 1e-5f);
  }
  __syncthreads();
  float gt = g[t], bt = bb[t];
  xout[((size_t)b*NOUT+m0)*DOUT + t] += (a0-bc[0][0])*bc[0][1]*gt + bt;
  xout[((size_t)b*NOUT+m1)*DOUT + t] += (a1-bc[1][0])*bc[1][1]*gt + bt;
  xout[((size_t)b*NOUT+m2)*DOUT + t] += (a2-bc[2][0])*bc[2][1]*gt + bt;
  xout[((size_t)b*NOUT+m3)*DOUT + t] += (a3-bc[3][0])*bc[3][1]*gt + bt;
}

// ---------------- MLP GEMM1 + GELU -> ht. 64 tokens x 96 hidden per block, TM=8 TN=3
__global__ __launch_bounds__(256) void k_mlp1(const float* __restrict__ xout,
                                              const float* __restrict__ w1_4, const float* __restrict__ b1,
                                              float* __restrict__ ht) {
  __shared__ float xt[64][196];
  int tok0 = blockIdx.x * 64;
  int h0 = blockIdx.y * 96;
  int t = threadIdx.x;
  const float4* xp = (const float4*)(xout + (size_t)tok0*DOUT);
  for (int i = t; i < 64*48; i += 256) {
    int tok = i / 48, q = i % 48;
    *(float4*)&xt[tok][q*4] = xp[i];
  }
  __syncthreads();
  int ol = t & 31, tg = t >> 5;   // 8 groups x 8 tokens
  float acc[8][3];
  #pragma unroll
  for (int i = 0; i < 8; i++) { acc[i][0]=0.f; acc[i][1]=0.f; acc[i][2]=0.f; }
  const float4* wp = (const float4*)w1_4 + h0 + ol;
  for (int e4 = 0; e4 < 48; e4++) {
    float4 w0 = wp[0], w1v = wp[32], w2v = wp[64];
    #pragma unroll
    for (int i = 0; i < 8; i++) {
      float4 xv = *(const float4*)&xt[tg*8+i][e4*4];
      acc[i][0] += xv.x*w0.x + xv.y*w0.y + xv.z*w0.z + xv.w*w0.w;
      acc[i][1] += xv.x*w1v.x + xv.y*w1v.y + xv.z*w1v.z + xv.w*w1v.w;
      acc[i][2] += xv.x*w2v.x + xv.y*w2v.y + xv.z*w2v.z + xv.w*w2v.w;
    }
    wp += 384;
  }
  #pragma unroll
  for (int j = 0; j < 3; j++) {
    int hh = h0 + ol + 32*j;
    float bv = b1[hh];
    #pragma unroll
    for (int i = 0; i < 8; i++) {
      float v = acc[i][j] + bv;
      v = 0.5f*v*(1.0f + erff(v*0.70710678118f));
      ht[(size_t)(tok0 + tg*8 + i)*HID + hh] = v;
    }
  }
}

// ---------------- MLP GEMM2 + LN + residual (+dout) + LN + next-iter q. 16 tok/block
__global__ __launch_bounds__(256) void k_mlpq(float* __restrict__ xout,
                                              const float* __restrict__ ht,
                                              const float* __restrict__ w2_4, const float* __restrict__ b2,
                                              const float* __restrict__ g, const float* __restrict__ bb,
                                              const float* __restrict__ qw4,
                                              const float* __restrict__ lng, const float* __restrict__ lnb,
                                              float* __restrict__ qb,
                                              float* __restrict__ dout, int last) {
  __shared__ float hs[16][388];
  __shared__ float xt[16][196];
  int tok0 = blockIdx.x * 16;
  int t = threadIdx.x;
  const float4* hp = (const float4*)(ht + (size_t)tok0*HID);
  for (int i = t; i < 16*96; i += 256) {
    int tok = i / 96, q = i % 96;
    *(float4*)&hs[tok][q*4] = hp[i];
  }
  __syncthreads();
  int ol = t & 31, tg = t >> 5;   // 8 groups x 2 tokens
  float acc[2][6];
  #pragma unroll
  for (int i = 0; i < 2; i++)
    #pragma unroll
    for (int j = 0; j < 6; j++) acc[i][j] = 0.f;
  const float4* wp = (const float4*)w2_4 + ol;
  for (int h4 = 0; h4 < 96; h4++) {
    float4 w[6];
    #pragma unroll
    for (int j = 0; j < 6; j++) w[j] = wp[32*j];
    #pragma unroll
    for (int i = 0; i < 2; i++) {
      float4 hv = *(const float4*)&hs[tg*2+i][h4*4];
      #pragma unroll
      for (int j = 0; j < 6; j++)
        acc[i][j] += hv.x*w[j].x + hv.y*w[j].y + hv.z*w[j].z + hv.w*w[j].w;
    }
    wp += 192;
  }
  #pragma unroll
  for (int i = 0; i < 2; i++) {
    int tl = tg*2 + i;
    int tok = tok0 + tl;
    float v[6], s = 0.f, sq = 0.f;
    #pragma unroll
    for (int j = 0; j < 6; j++) {
      v[j] = acc[i][j] + b2[ol + 32*j];
      s += v[j]; sq += v[j]*v[j];
    }
    #pragma unroll
    for (int off = 16; off; off >>= 1) { s += __shfl_xor(s, off, 32); sq += __shfl_xor(sq, off, 32); }
    float mu = s * (1.f/192.f);
    float var = sq * (1.f/192.f) - mu*mu;
    float rs = rsqrtf(var + 1e-5f);
    #pragma unroll
    for (int j = 0; j < 6; j++) {
      int o = ol + 32*j;
      float nv = (v[j] - mu)*rs*g[o] + bb[o];
      size_t gi = (size_t)tok*DOUT + o;
      float nx = xout[gi] + nv;
      xout[gi] = nx;
      if (last) dout[gi] = nx;
      xt[tl][o] = nx;
    }
  }
  if (last) return;
  __syncthreads();
  // LN (ln_out) on xt, 16-lane subgroups
  {
    int tok16 = t >> 4, l16 = t & 15;
    float vv[12], s = 0.f, sq = 0.f;
    #pragma unroll
    for (int j = 0; j < 12; j++) {
      float v = xt[tok16][l16 + 16*j];
      vv[j] = v; s += v; sq += v*v;
    }
    #pragma unroll
    for (int off = 8; off; off >>= 1) { s += __shfl_xor(s, off, 16); sq += __shfl_xor(sq, off, 16); }
    float mu = s * (1.f/192.f);
    float var = sq * (1.f/192.f) - mu*mu;
    float rs = rsqrtf(var + 1e-5f);
    __syncthreads();
    #pragma unroll
    for (int j = 0; j < 12; j++) {
      int e = l16 + 16*j;
      xt[tok16][e] = (vv[j]-mu)*rs*lng[e] + lnb[e];
    }
  }
  __syncthreads();
  // q-GEMM
  float qa[2][3];
  #pragma unroll
  for (int i = 0; i < 2; i++) { qa[i][0]=0.f; qa[i][1]=0.f; qa[i][2]=0.f; }
  const float4* qp = (const float4*)qw4 + ol;
  for (int e4 = 0; e4 < 48; e4++) {
    float4 w0 = qp[0], w1 = qp[32], w2 = qp[64];
    #pragma unroll
    for (int i = 0; i < 2; i++) {
      float4 xv = *(const float4*)&xt[tg*2+i][e4*4];
      qa[i][0] += xv.x*w0.x + xv.y*w0.y + xv.z*w0.z + xv.w*w0.w;
      qa[i][1] += xv.x*w1.x + xv.y*w1.y + xv.z*w1.z + xv.w*w1.w;
      qa[i][2] += xv.x*w2.x + xv.y*w2.y + xv.z*w2.z + xv.w*w2.w;
    }
    qp += 96;
  }
  #pragma unroll
  for (int i = 0; i < 2; i++)
    #pragma unroll
    for (int j = 0; j < 3; j++)
      qb[(size_t)(tok0 + tg*2 + i)*DIN + ol + 32*j] = qa[i][j];
}

extern "C" void kernel_launch(void* const* d_in, const int* in_sizes, int n_in,
                              void* d_out, int out_size, void* d_ws, size_t ws_size,
                              hipStream_t stream) {
  (void)in_sizes; (void)n_in; (void)ws_size; (void)out_size;
  const float* x        = (const float*)d_in[0];
  const float* conv_w   = (const float*)d_in[1];
  const float* q_w      = (const float*)d_in[2];
  const float* k_w      = (const float*)d_in[3];
  const float* v_w      = (const float*)d_in[4];
  const float* mlp_w1   = (const float*)d_in[5];
  const float* mlp_b1   = (const float*)d_in[6];
  const float* mlp_w2   = (const float*)d_in[7];
  const float* mlp_b2   = (const float*)d_in[8];
  const float* ln_in_g  = (const float*)d_in[9];
  const float* ln_in_b  = (const float*)d_in[10];
  const float* ln_out_g = (const float*)d_in[11];
  const float* ln_out_b = (const float*)d_in[12];
  const float* ln_attn_g= (const float*)d_in[13];
  const float* ln_attn_b= (const float*)d_in[14];
  const float* ln_mlp_g = (const float*)d_in[15];
  const float* ln_mlp_b = (const float*)d_in[16];
  const float* tau      = (const float*)d_in[17];
  const float* rpb      = (const float*)d_in[18];
  const int*   qidx     = (const int*)d_in[20];

  float* out = (float*)d_out;
  float* aups  = out + 1204224;       // 8*784*192
  float* adown = out + 20873216;      // + 8*3136*784

  float* ws   = (float*)d_ws;
  float* wct  = ws;                   // 165888
  float* wkv4 = wct + 165888;         // 27648
  float* qw4  = wkv4 + 27648;         // 18432
  float* w1_4 = qw4 + 18432;          // 73728
  float* w2_4 = w1_4 + 73728;         // 73728
  float* bias9= w2_4 + 73728;         // 28224
  float* kvb  = bias9 + 28224;        // 25088*288
  float* seed0= kvb + (size_t)TOK_IN*288;     // 6272*192
  float* seed1= seed0 + (size_t)TOK_OUT*DOUT; // 6272*192
  float* xo   = seed1 + (size_t)TOK_OUT*DOUT; // 6272*192
  float* qb   = xo + (size_t)TOK_OUT*DOUT;    // 6272*96
  float* htb  = qb + (size_t)TOK_OUT*DIN;     // 6272*384

  k_tr<<<1515, 256, 0, stream>>>(conv_w, k_w, v_w, q_w, mlp_w1, mlp_w2, rpb, qidx,
                                 wct, wkv4, qw4, w1_4, w2_4, bias9);
  k_conv<<<dim3(28, 4, 8), 224, 0, stream>>>(x, wct, seed0, seed1);
  k_lnq<<<TOK_OUT/16, 256, 0, stream>>>(seed0, seed1, qw4, ln_out_g, ln_out_b, xo, qb);
  k_kv<<<TOK_IN/64, 512, 0, stream>>>(x, wkv4, ln_in_g, ln_in_b, kvb);

  for (int it = 0; it < 3; it++) {
    k_attn1<<<TOK_IN/4, 256, 0, stream>>>(kvb, qb, tau, bias9, aups, adown, it == 0);
    k_upd<<<dim3(14, 14, NB), 192, 0, stream>>>(aups, kvb, xo, ln_attn_g, ln_attn_b,
                                                adown, it == 2);
    k_mlp1<<<dim3(TOK_OUT/64, 4), 256, 0, stream>>>(xo, w1_4, mlp_b1, htb);
    k_mlpq<<<TOK_OUT/16, 256, 0, stream>>>(xo, htb, w2_4, mlp_b2,
                                           ln_mlp_g, ln_mlp_b,
                                           qw4, ln_out_g, ln_out_b, qb,
                                           out, it == 2);
  }
}

// Round 10
// 777.758 us; speedup vs baseline: 1.3835x; 1.0752x over previous
//
#include <hip/hip_runtime.h>
#include <hip/hip_bf16.h>
#include <math.h>

#define NB 8
#define NIN 3136
#define NOUT 784
#define DIN 96
#define DOUT 192
#define HID 384
#define TOK_IN (NB*NIN)    // 25088
#define TOK_OUT (NB*NOUT)  // 6272

// ---------------- window helper
__device__ __forceinline__ void window9(int n, int* ms, bool* dup) {
  int r = n / 56, c = n % 56;
  int rb = r >> 1, cb = c >> 1;
  #pragma unroll
  for (int j = 0; j < 9; j++) {
    int ro = rb + (j/3) - 1; ro = ro < 0 ? 0 : (ro > 27 ? 27 : ro);
    int co = cb + (j%3) - 1; co = co < 0 ? 0 : (co > 27 ? 27 : co);
    ms[j] = ro*28 + co;
  }
  #pragma unroll
  for (int j = 0; j < 9; j++) {
    bool d = false;
    #pragma unroll
    for (int i = 0; i < j; i++) d = d || (ms[i] == ms[j]);
    dup[j] = d;
  }
}

// ---------------- weight transposes + bias9 table (once per launch)
// wct  : [ch=4][kh][ci4m=6][kw][co][4]   (ci = ch*24 + ci4m*4 + q)
// wkv4 : [e4][288][4]   (cols 0..95 = k_w, 96..287 = v_w)
// qw4  : [e4][96][4]
// w1_4 : [e4][384][4]
// w2_4 : [h4][192][4]
// bias9: [n][9] = rpb[qidx[n, ms_j(n)]]
__global__ void k_tr(const float* __restrict__ cw, const float* __restrict__ kw,
                     const float* __restrict__ vw, const float* __restrict__ qw,
                     const float* __restrict__ w1, const float* __restrict__ w2,
                     const float* __restrict__ rpb, const int* __restrict__ qidx,
                     float* __restrict__ wct, float* __restrict__ wkv4, float* __restrict__ qw4,
                     float* __restrict__ w1_4, float* __restrict__ w2_4,
                     float* __restrict__ bias9) {
  int i = blockIdx.x * 256 + threadIdx.x;
  if (i < 165888) {
    int q = i & 3; int t1 = i >> 2;
    int co = t1 % 192; int t2 = t1 / 192;
    int kwi = t2 % 3; int t3 = t2 / 3;
    int ci4m = t3 % 6; int t4 = t3 / 6;
    int kh = t4 % 3; int ch = t4 / 3;      // ch in [0,4)
    wct[i] = cw[((co*96 + ch*24 + ci4m*4 + q)*3 + kh)*3 + kwi];
  } else if (i < 165888 + 27648) {
    int j = i - 165888; int q = j & 3; int rest = j >> 2;
    int o = rest % 288; int e = (rest / 288)*4 + q;
    wkv4[j] = (o < 96) ? kw[o*96 + e] : vw[(o-96)*96 + e];
  } else if (i < 165888 + 27648 + 18432) {
    int j = i - 165888 - 27648; int q = j & 3; int rest = j >> 2;
    int o = rest % 96; int e = (rest / 96)*4 + q;
    qw4[j] = qw[o*192 + e];
  } else if (i < 165888 + 27648 + 18432 + 73728) {
    int j = i - 165888 - 27648 - 18432; int q = j & 3; int rest = j >> 2;
    int hh = rest % 384; int e = (rest / 384)*4 + q;
    w1_4[j] = w1[hh*192 + e];
  } else if (i < 165888 + 27648 + 18432 + 73728 + 73728) {
    int j = i - 165888 - 27648 - 18432 - 73728; int q = j & 3; int rest = j >> 2;
    int o = rest % 192; int h = (rest / 192)*4 + q;
    w2_4[j] = w2[o*384 + h];
  } else if (i < 165888 + 27648 + 18432 + 73728 + 73728 + 28224) {
    int j = i - 165888 - 27648 - 18432 - 73728 - 73728;
    int j9 = j % 9; int n = j / 9;
    int ms[9]; bool dup[9];
    window9(n, ms, dup);
    bias9[j] = rpb[qidx[(size_t)n*NOUT + ms[j9]]];
  }
}

// ---------------- strided 3x3 conv seed, 4-way ci-split partial sums.
// grid (28 ho, 8 = half + 2*ch, 8 b), 224 thr = 7 groups x 32 lanes; TM=4 wo, TN=3 co.
__global__ __launch_bounds__(224, 4) void k_conv(const float* __restrict__ x,
                                                 const float* __restrict__ wct,
                                                 float* __restrict__ s0, float* __restrict__ s1,
                                                 float* __restrict__ s2, float* __restrict__ s3) {
  __shared__ float xs[3][58][24];   // 16.7 KB
  int ho = blockIdx.x;
  int half = blockIdx.y & 1, ch = blockIdx.y >> 1;   // ch in [0,4)
  int b = blockIdx.z;
  int t = threadIdx.x;
  const float* xb0 = x + (size_t)b*NIN*DIN + ch*24;
  for (int i = t; i < 3*58*6; i += 224) {
    int q = i % 6; int rest = i / 6;
    int col = rest % 58; int kh = rest / 58;
    int h = 2*ho - 1 + kh, c = col - 1;
    float4 v = make_float4(0.f,0.f,0.f,0.f);
    if (h >= 0 && h < 56 && c >= 0 && c < 56)
      v = *(const float4*)(xb0 + ((size_t)h*56 + c)*DIN + q*4);
    *(float4*)&xs[kh][col][q*4] = v;
  }
  __syncthreads();
  int ol = t & 31, tg = t >> 5;       // tg in [0,7): wo = 4tg..4tg+3
  int co = half*96 + ol;
  float acc[4][3];
  #pragma unroll
  for (int i = 0; i < 4; i++) { acc[i][0]=0.f; acc[i][1]=0.f; acc[i][2]=0.f; }
  #pragma unroll
  for (int kh = 0; kh < 3; kh++) {
    const float4* wp = (const float4*)wct + (size_t)(ch*3 + kh)*3456 + co;
    const float* xb = &xs[kh][8*tg][0];
    #pragma unroll
    for (int ci4 = 0; ci4 < 6; ci4++) {
      float4 xr[9];
      #pragma unroll
      for (int c = 0; c < 9; c++) xr[c] = *(const float4*)(xb + c*24);
      #pragma unroll
      for (int kwv = 0; kwv < 3; kwv++) {
        float4 w0 = wp[kwv*192], w1 = wp[kwv*192 + 32], w2 = wp[kwv*192 + 64];
        #pragma unroll
        for (int i = 0; i < 4; i++) {
          float4 xv = xr[2*i + kwv];
          acc[i][0] += xv.x*w0.x + xv.y*w0.y + xv.z*w0.z + xv.w*w0.w;
          acc[i][1] += xv.x*w1.x + xv.y*w1.y + xv.z*w1.z + xv.w*w1.w;
          acc[i][2] += xv.x*w2.x + xv.y*w2.y + xv.z*w2.z + xv.w*w2.w;
        }
      }
      wp += 576; xb += 4;
    }
  }
  float* sp = (ch == 0) ? s0 : (ch == 1) ? s1 : (ch == 2) ? s2 : s3;
  #pragma unroll
  for (int i = 0; i < 4; i++)
    #pragma unroll
    for (int j = 0; j < 3; j++)
      sp[((size_t)b*NOUT + ho*28 + 4*tg + i)*DOUT + co + 32*j] = acc[i][j];
}

// ---------------- seed-sum(4) + LN -> xo, + LN + q-GEMM -> qb. 16 tok/block, 256 thr
__global__ __launch_bounds__(256) void k_lnq(const float* __restrict__ s0, const float* __restrict__ s1,
                                             const float* __restrict__ s2, const float* __restrict__ s3,
                                             const float* __restrict__ qw4,
                                             const float* __restrict__ lng, const float* __restrict__ lnb,
                                             float* __restrict__ xo, float* __restrict__ qb) {
  __shared__ float xt[16][196];
  int tok0 = blockIdx.x * 16;
  int t = threadIdx.x;
  int tok16 = t >> 4, l16 = t & 15;
  size_t base = (size_t)(tok0 + tok16)*DOUT;
  float v[12], s = 0.f, sq = 0.f;
  #pragma unroll
  for (int j = 0; j < 12; j++) {
    int e = l16 + 16*j;
    float vv = s0[base + e] + s1[base + e] + s2[base + e] + s3[base + e];
    v[j] = vv; s += vv; sq += vv*vv;
  }
  #pragma unroll
  for (int off = 8; off; off >>= 1) { s += __shfl_xor(s, off, 16); sq += __shfl_xor(sq, off, 16); }
  float mu = s * (1.f/192.f);
  float var = sq * (1.f/192.f) - mu*mu;
  float rs = rsqrtf(var + 1e-5f);
  float s2a = 0.f, sq2 = 0.f;
  #pragma unroll
  for (int j = 0; j < 12; j++) {
    int e = l16 + 16*j;
    float y = (v[j]-mu)*rs*lng[e] + lnb[e];
    xo[base + e] = y;
    v[j] = y; s2a += y; sq2 += y*y;
  }
  #pragma unroll
  for (int off = 8; off; off >>= 1) { s2a += __shfl_xor(s2a, off, 16); sq2 += __shfl_xor(sq2, off, 16); }
  float mu2 = s2a * (1.f/192.f);
  float var2 = sq2 * (1.f/192.f) - mu2*mu2;
  float rs2 = rsqrtf(var2 + 1e-5f);
  #pragma unroll
  for (int j = 0; j < 12; j++) {
    int e = l16 + 16*j;
    xt[tok16][e] = (v[j]-mu2)*rs2*lng[e] + lnb[e];
  }
  __syncthreads();
  int ol = t & 31, tg = t >> 5;
  float acc[2][3];
  #pragma unroll
  for (int i = 0; i < 2; i++) { acc[i][0]=0.f; acc[i][1]=0.f; acc[i][2]=0.f; }
  const float4* wp = (const float4*)qw4 + ol;
  for (int e4 = 0; e4 < 48; e4++) {
    float4 w0 = wp[0], w1 = wp[32], w2 = wp[64];
    #pragma unroll
    for (int i = 0; i < 2; i++) {
      float4 xv = *(const float4*)&xt[tg*2+i][e4*4];
      acc[i][0] += xv.x*w0.x + xv.y*w0.y + xv.z*w0.z + xv.w*w0.w;
      acc[i][1] += xv.x*w1.x + xv.y*w1.y + xv.z*w1.z + xv.w*w1.w;
      acc[i][2] += xv.x*w2.x + xv.y*w2.y + xv.z*w2.z + xv.w*w2.w;
    }
    wp += 96;
  }
  #pragma unroll
  for (int i = 0; i < 2; i++)
    #pragma unroll
    for (int j = 0; j < 3; j++)
      qb[(size_t)(tok0 + tg*2 + i)*DIN + ol + 32*j] = acc[i][j];
}

// ---------------- kv = LN(x) @ [k_w|v_w]^T, LN fused. 32 tokens/block, 256 thr, TM=4
__global__ __launch_bounds__(256) void k_kv(const float* __restrict__ x,
                                            const float* __restrict__ wkv4,
                                            const float* __restrict__ lng, const float* __restrict__ lnb,
                                            float* __restrict__ kvb) {
  __shared__ float xt[32][100];
  int tok0 = blockIdx.x * 32;
  int t = threadIdx.x;
  const float4* xp = (const float4*)(x + (size_t)tok0*DIN);
  for (int i = t; i < 32*24; i += 256) {
    int tok = i / 24, q = i % 24;
    *(float4*)&xt[tok][q*4] = xp[i];
  }
  __syncthreads();
  int tok8 = t >> 3, l8 = t & 7;
  float vv[12], s = 0.f, sq = 0.f;
  #pragma unroll
  for (int j = 0; j < 12; j++) {
    float v = xt[tok8][l8 + 8*j];
    vv[j] = v; s += v; sq += v*v;
  }
  #pragma unroll
  for (int off = 4; off; off >>= 1) { s += __shfl_xor(s, off, 8); sq += __shfl_xor(sq, off, 8); }
  float mu = s * (1.f/96.f);
  float var = sq * (1.f/96.f) - mu*mu;
  float rs = rsqrtf(var + 1e-5f);
  #pragma unroll
  for (int j = 0; j < 12; j++) {
    int e = l8 + 8*j;
    xt[tok8][e] = (vv[j]-mu)*rs*lng[e] + lnb[e];
  }
  __syncthreads();
  int ol = t & 31, tg = t >> 5;     // 8 groups x 4 tokens
  float acc[4][9];
  #pragma unroll
  for (int i = 0; i < 4; i++)
    #pragma unroll
    for (int j = 0; j < 9; j++) acc[i][j] = 0.f;
  const float4* wp = (const float4*)wkv4 + ol;
  for (int e4 = 0; e4 < 24; e4++) {
    float4 w[9];
    #pragma unroll
    for (int j = 0; j < 9; j++) w[j] = wp[32*j];
    #pragma unroll
    for (int i = 0; i < 4; i++) {
      float4 xv = *(const float4*)&xt[tg*4+i][e4*4];
      #pragma unroll
      for (int j = 0; j < 9; j++)
        acc[i][j] += xv.x*w[j].x + xv.y*w[j].y + xv.z*w[j].z + xv.w*w[j].w;
    }
    wp += 288;
  }
  #pragma unroll
  for (int i = 0; i < 4; i++)
    #pragma unroll
    for (int j = 0; j < 9; j++)
      kvb[(size_t)(tok0 + tg*4 + i)*288 + ol + 32*j] = acc[i][j];
}

// ---------------- sparse logits + softmax + a_ups. TWO tokens per wave (32-lane halves).
// zmode: also write full zero rows (aups with embedded values, adown zeros).
__global__ __launch_bounds__(256) void k_attn1(const float* __restrict__ kvb,
                                               const float* __restrict__ qb,
                                               const float* __restrict__ tau,
                                               const float* __restrict__ bias9,
                                               float* __restrict__ aups,
                                               float* __restrict__ adown, int zmode) {
  int t = threadIdx.x;
  int half = (t >> 5) & 1, ll = t & 31;
  int tid = blockIdx.x * 8 + (t >> 6) * 2 + half;   // 8 tokens per 256-thr block
  int b = tid / NIN, n = tid % NIN;
  int ms[9]; bool dup[9];
  window9(n, ms, dup);
  const float* kp = kvb + (size_t)tid * 288;
  float k0 = kp[ll], k1 = kp[32 + ll], k2 = kp[64 + ll];
  float et = expf(tau[0]);
  float p[9];
  #pragma unroll
  for (int j = 0; j < 9; j++) {
    const float* qp = qb + (size_t)(b*NOUT + ms[j]) * DIN;
    p[j] = k0 * qp[ll] + k1 * qp[32 + ll] + k2 * qp[64 + ll];
  }
  #pragma unroll
  for (int off = 16; off; off >>= 1)
    #pragma unroll
    for (int j = 0; j < 9; j++) p[j] += __shfl_xor(p[j], off, 32);
  const float* bp = bias9 + (size_t)n*9;
  float lg[9];
  #pragma unroll
  for (int j = 0; j < 9; j++)
    lg[j] = dup[j] ? -1e30f : p[j] * et + bp[j];
  float mx = lg[0];
  #pragma unroll
  for (int j = 1; j < 9; j++) mx = fmaxf(mx, lg[j]);
  float s = 0.f, ex[9];
  #pragma unroll
  for (int j = 0; j < 9; j++) { ex[j] = dup[j] ? 0.f : expf(lg[j] - mx); s += ex[j]; }
  float inv = 1.0f / s;
  if (zmode) {
    // full-row write: zeros + embedded values (all lanes of the half know all a_j)
    float* ap = aups + (size_t)tid*NOUT;
    float* dp = adown + (size_t)tid*NOUT;
    #pragma unroll
    for (int k = 0; k < 25; k++) {
      int e = ll + 32*k;
      if (e < NOUT) {
        float v = 0.f;
        #pragma unroll
        for (int j = 0; j < 9; j++)
          if (!dup[j] && e == ms[j]) v = ex[j] * inv;
        ap[e] = v;
        dp[e] = 0.f;
      }
    }
  } else {
    #pragma unroll
    for (int j = 0; j < 9; j++) {
      if (ll == j && !dup[j])
        aups[(size_t)tid*NOUT + ms[j]] = ex[j] * inv;
    }
  }
}

// ---------------- updates gather + LOCAL colsum + LN + residual (+ a_down last iter)
__global__ __launch_bounds__(192) void k_upd(const float* __restrict__ aups,
                                             const float* __restrict__ kvb,
                                             float* __restrict__ xout,
                                             const float* __restrict__ g,
                                             const float* __restrict__ bb,
                                             float* __restrict__ adown, int wadown) {
  __shared__ float avals[4][64];
  __shared__ float red[4][3][2];
  __shared__ float bc[4][2];
  __shared__ float csv[4];
  int b = blockIdx.z;
  int ro0 = blockIdx.y*2, co0 = blockIdx.x*2;
  int r0 = 2*ro0 - 2; if (r0 < 0) r0 = 0;
  int r1 = 2*ro0 + 5; if (r1 > 55) r1 = 55;
  int c0 = 2*co0 - 2; if (c0 < 0) c0 = 0;
  int c1 = 2*co0 + 5; if (c1 > 55) c1 = 55;
  int nr = r1 - r0 + 1, nc = c1 - c0 + 1, cnt = nr*nc;
  int t = threadIdx.x;
  int m0 = ro0*28 + co0, m1 = m0+1, m2 = m0+28, m3 = m0+29;
  if (t < cnt) {
    int ri = t / nc, ci = t % nc;
    int n = (r0 + ri)*56 + (c0 + ci);
    const float* ap = aups + ((size_t)b*NIN + n)*NOUT;
    avals[0][t] = ap[m0]; avals[1][t] = ap[m1];
    avals[2][t] = ap[m2]; avals[3][t] = ap[m3];
  } else if (t < 64) {
    avals[0][t] = 0.f; avals[1][t] = 0.f; avals[2][t] = 0.f; avals[3][t] = 0.f;
  }
  __syncthreads();
  if (t < 64) {    // colsum over the contributor rect (covers all contributors; rest are 0)
    float cv0 = avals[0][t], cv1 = avals[1][t], cv2 = avals[2][t], cv3 = avals[3][t];
    #pragma unroll
    for (int off = 32; off; off >>= 1) {
      cv0 += __shfl_xor(cv0, off); cv1 += __shfl_xor(cv1, off);
      cv2 += __shfl_xor(cv2, off); cv3 += __shfl_xor(cv3, off);
    }
    if (t == 0) { csv[0]=cv0; csv[1]=cv1; csv[2]=cv2; csv[3]=cv3; }
  }
  __syncthreads();
  float a0=0.f, a1=0.f, a2=0.f, a3=0.f;
  int i = 0;
  for (int ri = 0; ri < nr; ri++) {
    int nbase = (r0 + ri)*56 + c0;
    for (int ci = 0; ci < nc; ci++, i++) {
      float vv = kvb[((size_t)b*NIN + nbase + ci)*288 + 96 + t];
      a0 += avals[0][i]*vv; a1 += avals[1][i]*vv;
      a2 += avals[2][i]*vv; a3 += avals[3][i]*vv;
    }
  }
  float inv0 = 1.0f/(csv[0]+1e-8f);
  float inv1 = 1.0f/(csv[1]+1e-8f);
  float inv2 = 1.0f/(csv[2]+1e-8f);
  float inv3 = 1.0f/(csv[3]+1e-8f);
  if (wadown && t < cnt) {
    int ri = t / nc, ci = t % nc;
    int n = (r0 + ri)*56 + (c0 + ci);
    float* dp = adown + ((size_t)b*NIN + n)*NOUT;
    dp[m0] = avals[0][t]*inv0; dp[m1] = avals[1][t]*inv1;
    dp[m2] = avals[2][t]*inv2; dp[m3] = avals[3][t]*inv3;
  }
  a0 *= inv0; a1 *= inv1; a2 *= inv2; a3 *= inv3;
  float s0=a0,s1=a1,s2=a2,s3=a3, q0=a0*a0,q1=a1*a1,q2=a2*a2,q3=a3*a3;
  #pragma unroll
  for (int off = 32; off; off >>= 1) {
    s0 += __shfl_xor(s0, off); q0 += __shfl_xor(q0, off);
    s1 += __shfl_xor(s1, off); q1 += __shfl_xor(q1, off);
    s2 += __shfl_xor(s2, off); q2 += __shfl_xor(q2, off);
    s3 += __shfl_xor(s3, off); q3 += __shfl_xor(q3, off);
  }
  int w = t >> 6, l = t & 63;
  if (l == 0) {
    red[0][w][0]=s0; red[0][w][1]=q0;
    red[1][w][0]=s1; red[1][w][1]=q1;
    red[2][w][0]=s2; red[2][w][1]=q2;
    red[3][w][0]=s3; red[3][w][1]=q3;
  }
  __syncthreads();
  if (t < 4) {
    float S = red[t][0][0]+red[t][1][0]+red[t][2][0];
    float Q = red[t][0][1]+red[t][1][1]+red[t][2][1];
    float mu = S * (1.0f/192.0f);
    float var = Q * (1.0f/192.0f) - mu*mu;
    bc[t][0] = mu; bc[t][1] = rsqrtf(var + 1e-5f);
  }
  __syncthreads();
  float gt = g[t], bt = bb[t];
  xout[((size_t)b*NOUT+m0)*DOUT + t] += (a0-bc[0][0])*bc[0][1]*gt + bt;
  xout[((size_t)b*NOUT+m1)*DOUT + t] += (a1-bc[1][0])*bc[1][1]*gt + bt;
  xout[((size_t)b*NOUT+m2)*DOUT + t] += (a2-bc[2][0])*bc[2][1]*gt + bt;
  xout[((size_t)b*NOUT+m3)*DOUT + t] += (a3-bc[3][0])*bc[3][1]*gt + bt;
}

// ---------------- MLP GEMM1 + GELU -> ht. 32 tokens x 96 hidden per block, TM=4 TN=3
__global__ __launch_bounds__(256) void k_mlp1(const float* __restrict__ xout,
                                              const float* __restrict__ w1_4, const float* __restrict__ b1,
                                              float* __restrict__ ht) {
  __shared__ float xt[32][196];
  int tok0 = blockIdx.x * 32;
  int h0 = blockIdx.y * 96;
  int t = threadIdx.x;
  const float4* xp = (const float4*)(xout + (size_t)tok0*DOUT);
  for (int i = t; i < 32*48; i += 256) {
    int tok = i / 48, q = i % 48;
    *(float4*)&xt[tok][q*4] = xp[i];
  }
  __syncthreads();
  int ol = t & 31, tg = t >> 5;   // 8 groups x 4 tokens
  float acc[4][3];
  #pragma unroll
  for (int i = 0; i < 4; i++) { acc[i][0]=0.f; acc[i][1]=0.f; acc[i][2]=0.f; }
  const float4* wp = (const float4*)w1_4 + h0 + ol;
  for (int e4 = 0; e4 < 48; e4++) {
    float4 w0 = wp[0], w1v = wp[32], w2v = wp[64];
    #pragma unroll
    for (int i = 0; i < 4; i++) {
      float4 xv = *(const float4*)&xt[tg*4+i][e4*4];
      acc[i][0] += xv.x*w0.x + xv.y*w0.y + xv.z*w0.z + xv.w*w0.w;
      acc[i][1] += xv.x*w1v.x + xv.y*w1v.y + xv.z*w1v.z + xv.w*w1v.w;
      acc[i][2] += xv.x*w2v.x + xv.y*w2v.y + xv.z*w2v.z + xv.w*w2v.w;
    }
    wp += 384;
  }
  #pragma unroll
  for (int j = 0; j < 3; j++) {
    int hh = h0 + ol + 32*j;
    float bv = b1[hh];
    #pragma unroll
    for (int i = 0; i < 4; i++) {
      float v = acc[i][j] + bv;
      v = 0.5f*v*(1.0f + erff(v*0.70710678118f));
      ht[(size_t)(tok0 + tg*4 + i)*HID + hh] = v;
    }
  }
}

// ---------------- MLP GEMM2 + LN + residual (+dout) + LN + next-iter q. 16 tok/block
__global__ __launch_bounds__(256) void k_mlpq(float* __restrict__ xout,
                                              const float* __restrict__ ht,
                                              const float* __restrict__ w2_4, const float* __restrict__ b2,
                                              const float* __restrict__ g, const float* __restrict__ bb,
                                              const float* __restrict__ qw4,
                                              const float* __restrict__ lng, const float* __restrict__ lnb,
                                              float* __restrict__ qb,
                                              float* __restrict__ dout, int last) {
  __shared__ float hs[16][388];
  __shared__ float xt[16][196];
  int tok0 = blockIdx.x * 16;
  int t = threadIdx.x;
  const float4* hp = (const float4*)(ht + (size_t)tok0*HID);
  for (int i = t; i < 16*96; i += 256) {
    int tok = i / 96, q = i % 96;
    *(float4*)&hs[tok][q*4] = hp[i];
  }
  __syncthreads();
  int ol = t & 31, tg = t >> 5;   // 8 groups x 2 tokens
  float acc[2][6];
  #pragma unroll
  for (int i = 0; i < 2; i++)
    #pragma unroll
    for (int j = 0; j < 6; j++) acc[i][j] = 0.f;
  const float4* wp = (const float4*)w2_4 + ol;
  for (int h4 = 0; h4 < 96; h4++) {
    float4 w[6];
    #pragma unroll
    for (int j = 0; j < 6; j++) w[j] = wp[32*j];
    #pragma unroll
    for (int i = 0; i < 2; i++) {
      float4 hv = *(const float4*)&hs[tg*2+i][h4*4];
      #pragma unroll
      for (int j = 0; j < 6; j++)
        acc[i][j] += hv.x*w[j].x + hv.y*w[j].y + hv.z*w[j].z + hv.w*w[j].w;
    }
    wp += 192;
  }
  #pragma unroll
  for (int i = 0; i < 2; i++) {
    int tl = tg*2 + i;
    int tok = tok0 + tl;
    float v[6], s = 0.f, sq = 0.f;
    #pragma unroll
    for (int j = 0; j < 6; j++) {
      v[j] = acc[i][j] + b2[ol + 32*j];
      s += v[j]; sq += v[j]*v[j];
    }
    #pragma unroll
    for (int off = 16; off; off >>= 1) { s += __shfl_xor(s, off, 32); sq += __shfl_xor(sq, off, 32); }
    float mu = s * (1.f/192.f);
    float var = sq * (1.f/192.f) - mu*mu;
    float rs = rsqrtf(var + 1e-5f);
    #pragma unroll
    for (int j = 0; j < 6; j++) {
      int o = ol + 32*j;
      float nv = (v[j] - mu)*rs*g[o] + bb[o];
      size_t gi = (size_t)tok*DOUT + o;
      float nx = xout[gi] + nv;
      xout[gi] = nx;
      if (last) dout[gi] = nx;
      xt[tl][o] = nx;
    }
  }
  if (last) return;
  __syncthreads();
  // LN (ln_out) on xt, 16-lane subgroups
  {
    int tok16 = t >> 4, l16 = t & 15;
    float vv[12], s = 0.f, sq = 0.f;
    #pragma unroll
    for (int j = 0; j < 12; j++) {
      float v = xt[tok16][l16 + 16*j];
      vv[j] = v; s += v; sq += v*v;
    }
    #pragma unroll
    for (int off = 8; off; off >>= 1) { s += __shfl_xor(s, off, 16); sq += __shfl_xor(sq, off, 16); }
    float mu = s * (1.f/192.f);
    float var = sq * (1.f/192.f) - mu*mu;
    float rs = rsqrtf(var + 1e-5f);
    __syncthreads();
    #pragma unroll
    for (int j = 0; j < 12; j++) {
      int e = l16 + 16*j;
      xt[tok16][e] = (vv[j]-mu)*rs*lng[e] + lnb[e];
    }
  }
  __syncthreads();
  // q-GEMM
  float qa[2][3];
  #pragma unroll
  for (int i = 0; i < 2; i++) { qa[i][0]=0.f; qa[i][1]=0.f; qa[i][2]=0.f; }
  const float4* qp = (const float4*)qw4 + ol;
  for (int e4 = 0; e4 < 48; e4++) {
    float4 w0 = qp[0], w1 = qp[32], w2 = qp[64];
    #pragma unroll
    for (int i = 0; i < 2; i++) {
      float4 xv = *(const float4*)&xt[tg*2+i][e4*4];
      qa[i][0] += xv.x*w0.x + xv.y*w0.y + xv.z*w0.z + xv.w*w0.w;
      qa[i][1] += xv.x*w1.x + xv.y*w1.y + xv.z*w1.z + xv.w*w1.w;
      qa[i][2] += xv.x*w2.x + xv.y*w2.y + xv.z*w2.z + xv.w*w2.w;
    }
    qp += 96;
  }
  #pragma unroll
  for (int i = 0; i < 2; i++)
    #pragma unroll
    for (int j = 0; j < 3; j++)
      qb[(size_t)(tok0 + tg*2 + i)*DIN + ol + 32*j] = qa[i][j];
}

extern "C" void kernel_launch(void* const* d_in, const int* in_sizes, int n_in,
                              void* d_out, int out_size, void* d_ws, size_t ws_size,
                              hipStream_t stream) {
  (void)in_sizes; (void)n_in; (void)ws_size; (void)out_size;
  const float* x        = (const float*)d_in[0];
  const float* conv_w   = (const float*)d_in[1];
  const float* q_w      = (const float*)d_in[2];
  const float* k_w      = (const float*)d_in[3];
  const float* v_w      = (const float*)d_in[4];
  const float* mlp_w1   = (const float*)d_in[5];
  const float* mlp_b1   = (const float*)d_in[6];
  const float* mlp_w2   = (const float*)d_in[7];
  const float* mlp_b2   = (const float*)d_in[8];
  const float* ln_in_g  = (const float*)d_in[9];
  const float* ln_in_b  = (const float*)d_in[10];
  const float* ln_out_g = (const float*)d_in[11];
  const float* ln_out_b = (const float*)d_in[12];
  const float* ln_attn_g= (const float*)d_in[13];
  const float* ln_attn_b= (const float*)d_in[14];
  const float* ln_mlp_g = (const float*)d_in[15];
  const float* ln_mlp_b = (const float*)d_in[16];
  const float* tau      = (const float*)d_in[17];
  const float* rpb      = (const float*)d_in[18];
  const int*   qidx     = (const int*)d_in[20];

  float* out = (float*)d_out;
  float* aups  = out + 1204224;       // 8*784*192
  float* adown = out + 20873216;      // + 8*3136*784

  float* ws   = (float*)d_ws;
  float* wct  = ws;                   // 165888
  float* wkv4 = wct + 165888;         // 27648
  float* qw4  = wkv4 + 27648;         // 18432
  float* w1_4 = qw4 + 18432;          // 73728
  float* w2_4 = w1_4 + 73728;         // 73728
  float* bias9= w2_4 + 73728;         // 28224
  float* kvb  = bias9 + 28224;        // 25088*288
  float* seed0= kvb + (size_t)TOK_IN*288;     // 4 x 6272*192 (dead after k_lnq)
  float* seed1= seed0 + (size_t)TOK_OUT*DOUT;
  float* seed2= seed1 + (size_t)TOK_OUT*DOUT;
  float* seed3= seed2 + (size_t)TOK_OUT*DOUT;
  float* xo   = seed3 + (size_t)TOK_OUT*DOUT; // 6272*192
  float* qb   = xo + (size_t)TOK_OUT*DOUT;    // 6272*96
  float* htb  = seed0;                        // alias: seeds dead once k_lnq ran (6272*384 fits in 2 seeds)

  k_tr<<<1515, 256, 0, stream>>>(conv_w, k_w, v_w, q_w, mlp_w1, mlp_w2, rpb, qidx,
                                 wct, wkv4, qw4, w1_4, w2_4, bias9);
  k_conv<<<dim3(28, 8, 8), 224, 0, stream>>>(x, wct, seed0, seed1, seed2, seed3);
  k_lnq<<<TOK_OUT/16, 256, 0, stream>>>(seed0, seed1, seed2, seed3, qw4,
                                        ln_out_g, ln_out_b, xo, qb);
  k_kv<<<TOK_IN/32, 256, 0, stream>>>(x, wkv4, ln_in_g, ln_in_b, kvb);

  for (int it = 0; it < 3; it++) {
    k_attn1<<<TOK_IN/8, 256, 0, stream>>>(kvb, qb, tau, bias9, aups, adown, it == 0);
    k_upd<<<dim3(14, 14, NB), 192, 0, stream>>>(aups, kvb, xo, ln_attn_g, ln_attn_b,
                                                adown, it == 2);
    k_mlp1<<<dim3(TOK_OUT/32, 4), 256, 0, stream>>>(xo, w1_4, mlp_b1, htb);
    k_mlpq<<<TOK_OUT/16, 256, 0, stream>>>(xo, htb, w2_4, mlp_b2,
                                           ln_mlp_g, ln_mlp_b,
                                           qw4, ln_out_g, ln_out_b, qb,
                                           out, it == 2);
  }
}